// Round 7
// baseline (1830.284 us; speedup 1.0000x reference)
//
#include <hip/hip_runtime.h>
#include <math.h>

#define NN 100000
#define PADN 100096    // 1564*64
#define NBLK64 1564
#define NBLK128 782
#define HH 512
#define KK 128
#define BETA 100.0f
#define EPSF 1e-8f
#define ITERS 11
#define NSPLIT 128
#define NCHUNK (PADN / 64)  // 1564

typedef __attribute__((ext_vector_type(8))) short short8v;
typedef __attribute__((ext_vector_type(4))) float float4v;

typedef const __attribute__((address_space(1))) void* gas_t;
typedef __attribute__((address_space(3))) void* las_t;

__device__ __forceinline__ void gload16(const void* g, void* l) {
  __builtin_amdgcn_global_load_lds((gas_t)g, (las_t)l, 16, 0, 0);
}

__device__ __forceinline__ unsigned short f2bf(float x) {
  unsigned int u = __float_as_uint(x);
  unsigned int r = (u + 0x7fff + ((u >> 16) & 1)) >> 16;
  return (unsigned short)r;
}
__device__ __forceinline__ float bf2f(unsigned short b) {
  return __uint_as_float((unsigned int)b << 16);
}

__device__ __forceinline__ float wave_reduce_sum(float v) {
#pragma unroll
  for (int off = 32; off > 0; off >>= 1) v += __shfl_xor(v, off);
  return v;
}
__device__ __forceinline__ float softplusf(float x) {
  return fmaxf(x, 0.0f) + log1pf(expf(-fabsf(x)));
}

// ---- fused prep: inv_norm, colsum, posb (normalized bf16), pad-zero
__global__ void prep_kernel(const float* __restrict__ pos,
                            float* __restrict__ inv_norm,
                            float* __restrict__ colsum,
                            unsigned short* __restrict__ posb) {
  int t = threadIdx.x;
  int w = t >> 6, lane = t & 63;
  int gw = blockIdx.x * 4 + w;
  float cpart[8] = {0, 0, 0, 0, 0, 0, 0, 0};
  for (int row = gw; row < NN; row += 1024) {
    const float* p = pos + (size_t)row * HH + lane * 8;
    float4 f0 = *(const float4*)p;
    float4 f1 = *(const float4*)(p + 4);
    float v[8] = {f0.x, f0.y, f0.z, f0.w, f1.x, f1.y, f1.z, f1.w};
    float ss = 0.f;
#pragma unroll
    for (int u = 0; u < 8; ++u) {
      ss += v[u] * v[u];
      cpart[u] += v[u];
    }
    ss = wave_reduce_sum(ss);
    float inv = 1.0f / (sqrtf(ss) + EPSF);
    if (lane == 0) inv_norm[row] = inv;
    short8v o;
#pragma unroll
    for (int u = 0; u < 8; ++u) o[u] = (short)f2bf(v[u] * inv);
    *(short8v*)&posb[(size_t)row * HH + lane * 8] = o;
  }
  {
    int idx = blockIdx.x * 256 + t;
    if (idx < (PADN - NN) * HH / 8) {
      short8v z = (short8v){0, 0, 0, 0, 0, 0, 0, 0};
      *(short8v*)&posb[(size_t)NN * HH + idx * 8] = z;
    }
  }
  __shared__ float cs[HH];
  cs[t] = 0.f;
  cs[t + 256] = 0.f;
  __syncthreads();
#pragma unroll
  for (int u = 0; u < 8; ++u) atomicAdd(&cs[lane * 8 + u], cpart[u]);
  __syncthreads();
  atomicAdd(&colsum[t], cs[t]);
  atomicAdd(&colsum[t + 256], cs[t + 256]);
}

// ---- bf16 transpose posb -> posbT (posb is L3-hot)
__launch_bounds__(256)
__global__ void transpose_kernel(const unsigned short* __restrict__ posb,
                                 unsigned short* __restrict__ posbT) {
  __shared__ unsigned short tile[64][72];
  int t = threadIdx.x;
  int i0 = blockIdx.x * 64, h0 = blockIdx.y * 64;
  int r = t >> 2, cq = (t & 3) * 16;
#pragma unroll
  for (int q = 0; q < 2; ++q) {
    short8v v = *(const short8v*)&posb[(size_t)(i0 + r) * HH + h0 + cq + q * 8];
#pragma unroll
    for (int e = 0; e < 8; ++e) tile[cq + q * 8 + e][r] = (unsigned short)v[e];
  }
  __syncthreads();
  int h = t >> 2, iq = (t & 3) * 16;
#pragma unroll
  for (int q = 0; q < 2; ++q)
    *(short8v*)&posbT[(size_t)(h0 + h) * PADN + i0 + iq + q * 8] =
        *(const short8v*)&tile[h][iq + q * 8];
}

// ---- gs[h] = sigmoid(colsum[h]/N)
__global__ void gs_kernel(const float* __restrict__ colsum, float* __restrict__ gs) {
  int t = threadIdx.x;
  float m = colsum[t] * (1.0f / NN);
  gs[t] = 1.0f / (1.0f + expf(-m));
}

// ---- Ws[j] = sum_h W[j][h]*gs[h]
__global__ void wsum_kernel(const float* __restrict__ W, const float* __restrict__ gs,
                            float* __restrict__ Ws) {
  int w = threadIdx.x >> 6, lane = threadIdx.x & 63;
  int row = blockIdx.x * 4 + w;
  const float* Wr = W + (size_t)row * HH;
  float s = 0.f;
#pragma unroll
  for (int j = 0; j < 8; ++j) s += Wr[lane + 64 * j] * gs[lane + 64 * j];
  s = wave_reduce_sum(s);
  if (lane == 0) Ws[row] = s;
}

// ---- mub (bf16) = row / ||row|| from fp32 src; zero cluster_r. Used once on init.
__global__ void norm_mu_kernel(const float* __restrict__ src, unsigned short* __restrict__ mub,
                               float* __restrict__ cluster_r) {
  int k = blockIdx.x, t = threadIdx.x;
  float v0 = src[k * HH + t], v1 = src[k * HH + t + 256];
  float ss = v0 * v0 + v1 * v1;
  ss = wave_reduce_sum(ss);
  __shared__ float red[4];
  if ((t & 63) == 0) red[t >> 6] = ss;
  __syncthreads();
  float inv = 1.0f / sqrtf(red[0] + red[1] + red[2] + red[3]);
  mub[k * HH + t] = f2bf(v0 * inv);
  mub[k * HH + t + 256] = f2bf(v1 * inv);
  if (t == 0) cluster_r[k] = 0.f;
}

// ---- MFMA dist + fused softmax. BM=64, BK=64, 256 thr (2x2 waves), 3 blocks/CU.
// A,B LDS double-buffered + XOR swizzle.
__launch_bounds__(256, 3)
__global__ void dist_mfma(const unsigned short* __restrict__ posb,
                          const unsigned short* __restrict__ mub,
                          unsigned short* __restrict__ rbf,
                          unsigned short* __restrict__ rbfT,
                          float* __restrict__ cluster_r,
                          int write_rbf) {
  __shared__ __align__(16) unsigned short smem[24576];  // 48KB: As[2][4096] | Bs[2][8192]
  unsigned short* As0 = smem;
  unsigned short* Bs0 = smem + 8192;
  unsigned short* rT = smem;  // [128 c][72] epilogue alias (18.4KB)
  __shared__ float redM[2][64];
  __shared__ float redS[2][64];

  int t = threadIdx.x;
  int w = t >> 6, l = t & 63;
  int wr = w >> 1, wc = w & 1;
  int i0 = blockIdx.x * 64;

  float4v acc[2][4];
#pragma unroll
  for (int mi = 0; mi < 2; ++mi)
#pragma unroll
    for (int ni = 0; ni < 4; ++ni) acc[mi][ni] = (float4v){0.f, 0.f, 0.f, 0.f};

  int rsub = l >> 3;
  int scol = ((l & 7) ^ rsub) * 8;  // shorts

  auto stage = [&](int buf, int ch) {
    int h0 = ch * 64;
#pragma unroll
    for (int j = 0; j < 2; ++j) {
      int v = w * 2 + j;       // 0..7
      int row = v * 8 + rsub;  // 0..63
      gload16(posb + (size_t)(i0 + row) * HH + h0 + scol, As0 + buf * 4096 + v * 512);
    }
#pragma unroll
    for (int j = 0; j < 4; ++j) {
      int vb = w * 4 + j;        // 0..15
      int rowb = vb * 8 + rsub;  // 0..127
      gload16(mub + (size_t)rowb * HH + h0 + scol, Bs0 + buf * 8192 + vb * 512);
    }
  };

  stage(0, 0);
  __syncthreads();
  int cur = 0;
  for (int ch = 0; ch < 8; ++ch) {
    if (ch < 7) stage(cur ^ 1, ch + 1);
    const char* ab = (const char*)(As0 + cur * 4096);
    const char* bb = (const char*)(Bs0 + cur * 8192);
#pragma unroll
    for (int ks = 0; ks < 2; ++ks) {
      short8v af[2], bfr[4];
      int kb = ks * 64 + (l >> 4) * 16;
      int rx = ((l & 7) << 4);
#pragma unroll
      for (int mi = 0; mi < 2; ++mi) {
        int row = wr * 32 + mi * 16 + (l & 15);
        af[mi] = *(const short8v*)(ab + row * 128 + (kb ^ rx));
      }
#pragma unroll
      for (int ni = 0; ni < 4; ++ni) {
        int row = wc * 64 + ni * 16 + (l & 15);
        bfr[ni] = *(const short8v*)(bb + row * 128 + (kb ^ rx));
      }
#pragma unroll
      for (int mi = 0; mi < 2; ++mi)
#pragma unroll
        for (int ni = 0; ni < 4; ++ni)
          acc[mi][ni] = __builtin_amdgcn_mfma_f32_16x16x32_bf16(af[mi], bfr[ni], acc[mi][ni], 0, 0, 0);
    }
    __syncthreads();
    cur ^= 1;
  }

  // ---- softmax epilogue. row(local) = wr*32+mi*16+(l>>4)*4+j (0..63), col = wc*64+ni*16+(l&15)
  float wmax[2][4];
#pragma unroll
  for (int mi = 0; mi < 2; ++mi)
#pragma unroll
    for (int j = 0; j < 4; ++j) {
      float m = fmaxf(fmaxf(acc[mi][0][j], acc[mi][1][j]), fmaxf(acc[mi][2][j], acc[mi][3][j])) * BETA;
      m = fmaxf(m, __shfl_xor(m, 1));
      m = fmaxf(m, __shfl_xor(m, 2));
      m = fmaxf(m, __shfl_xor(m, 4));
      m = fmaxf(m, __shfl_xor(m, 8));
      wmax[mi][j] = m;
    }
  if ((l & 15) == 0) {
#pragma unroll
    for (int mi = 0; mi < 2; ++mi)
#pragma unroll
      for (int j = 0; j < 4; ++j)
        redM[wc][wr * 32 + mi * 16 + (l >> 4) * 4 + j] = wmax[mi][j];
  }
  __syncthreads();
  float fm[2][4];
#pragma unroll
  for (int mi = 0; mi < 2; ++mi)
#pragma unroll
    for (int j = 0; j < 4; ++j) {
      int row = wr * 32 + mi * 16 + (l >> 4) * 4 + j;
      fm[mi][j] = fmaxf(redM[0][row], redM[1][row]);
    }
#pragma unroll
  for (int mi = 0; mi < 2; ++mi)
#pragma unroll
    for (int j = 0; j < 4; ++j) {
      float s = 0.f;
#pragma unroll
      for (int ni = 0; ni < 4; ++ni) {
        float e = __expf(acc[mi][ni][j] * BETA - fm[mi][j]);
        acc[mi][ni][j] = e;
        s += e;
      }
      s += __shfl_xor(s, 1);
      s += __shfl_xor(s, 2);
      s += __shfl_xor(s, 4);
      s += __shfl_xor(s, 8);
      wmax[mi][j] = s;  // reuse
    }
  if ((l & 15) == 0) {
#pragma unroll
    for (int mi = 0; mi < 2; ++mi)
#pragma unroll
      for (int j = 0; j < 4; ++j)
        redS[wc][wr * 32 + mi * 16 + (l >> 4) * 4 + j] = wmax[mi][j];
  }
  __syncthreads();

  float cpart[4] = {0.f, 0.f, 0.f, 0.f};
#pragma unroll
  for (int mi = 0; mi < 2; ++mi)
#pragma unroll
    for (int j = 0; j < 4; ++j) {
      int row = wr * 32 + mi * 16 + (l >> 4) * 4 + j;
      float invs = 1.0f / (redS[0][row] + redS[1][row]);
      bool valid = (i0 + row) < NN;
#pragma unroll
      for (int ni = 0; ni < 4; ++ni) {
        float rv = acc[mi][ni][j] * invs;
        if (valid) cpart[ni] += rv;
        rT[(wc * 64 + ni * 16 + (l & 15)) * 72 + row] = f2bf(rv);
      }
    }
#pragma unroll
  for (int ni = 0; ni < 4; ++ni) {
    float c = cpart[ni];
    c += __shfl_xor(c, 16);
    c += __shfl_xor(c, 32);
    if (l < 16) atomicAdd(&cluster_r[wc * 64 + ni * 16 + l], c);
  }
  __syncthreads();

  {
    int c = t >> 1, half = t & 1;
    const unsigned short* src = &rT[c * 72 + half * 32];
    unsigned short* dst = &rbfT[(size_t)c * PADN + i0 + half * 32];
#pragma unroll
    for (int q = 0; q < 4; ++q)
      *(short8v*)(dst + q * 8) = *(const short8v*)(src + q * 8);
  }
  if (write_rbf) {
    int i = t >> 2, q = t & 3;
#pragma unroll
    for (int qq = 0; qq < 4; ++qq) {
      short8v v;
#pragma unroll
      for (int e = 0; e < 8; ++e) v[e] = (short)rT[(q * 32 + qq * 8 + e) * 72 + i];
      *(short8v*)&rbf[(size_t)(i0 + i) * KK + q * 32 + qq * 8] = v;
    }
  }
}

// ---- MFMA mu update. A (rbfT) + B (posbT) LDS double-buffered, XOR-swizzled.
__launch_bounds__(256, 2)
__global__ void muup_mfma(const unsigned short* __restrict__ rbfT,
                          const unsigned short* __restrict__ posbT,
                          unsigned short* __restrict__ part) {
  __shared__ __align__(16) unsigned short smem[32768];  // As[2][8192] | Bs[2][8192]
  unsigned short* As0 = smem;
  unsigned short* Bs0 = smem + 16384;
  int t = threadIdx.x;
  int w = t >> 6, l = t & 63;
  int wr = w >> 1, wc = w & 1;
  int ht = blockIdx.x, s = blockIdx.y;

  float4v acc[4][4];
#pragma unroll
  for (int mi = 0; mi < 4; ++mi)
#pragma unroll
    for (int ni = 0; ni < 4; ++ni) acc[mi][ni] = (float4v){0.f, 0.f, 0.f, 0.f};

  int rsub = l >> 3;
  int scol = ((l & 7) ^ rsub) * 8;  // shorts

  auto stage = [&](int buf, int ch) {
    size_t ib = (size_t)ch * 64;
#pragma unroll
    for (int j = 0; j < 4; ++j) {
      int v = w * 4 + j;
      int row = v * 8 + rsub;
      gload16(rbfT + (size_t)row * PADN + ib + scol, As0 + buf * 8192 + v * 512);
      gload16(posbT + (size_t)(ht * 128 + row) * PADN + ib + scol, Bs0 + buf * 8192 + v * 512);
    }
  };

  int ch = s;
  stage(0, ch);
  __syncthreads();
  int cur = 0;
  for (; ch < NCHUNK; ch += NSPLIT) {
    int nxt = ch + NSPLIT;
    if (nxt < NCHUNK) stage(cur ^ 1, nxt);
    const char* ab = (const char*)(As0 + cur * 8192);
    const char* bb = (const char*)(Bs0 + cur * 8192);
#pragma unroll
    for (int ks = 0; ks < 2; ++ks) {
      short8v af[4], bfr[4];
      int kb = ks * 64 + (l >> 4) * 16;
      int rx = ((l & 7) << 4);
#pragma unroll
      for (int mi = 0; mi < 4; ++mi) {
        int row = wr * 64 + mi * 16 + (l & 15);
        af[mi] = *(const short8v*)(ab + row * 128 + (kb ^ rx));
      }
#pragma unroll
      for (int ni = 0; ni < 4; ++ni) {
        int row = wc * 64 + ni * 16 + (l & 15);
        bfr[ni] = *(const short8v*)(bb + row * 128 + (kb ^ rx));
      }
#pragma unroll
      for (int mi = 0; mi < 4; ++mi)
#pragma unroll
        for (int ni = 0; ni < 4; ++ni)
          acc[mi][ni] = __builtin_amdgcn_mfma_f32_16x16x32_bf16(af[mi], bfr[ni], acc[mi][ni], 0, 0, 0);
    }
    __syncthreads();
    cur ^= 1;
  }
#pragma unroll
  for (int mi = 0; mi < 4; ++mi)
#pragma unroll
    for (int ni = 0; ni < 4; ++ni)
#pragma unroll
      for (int j = 0; j < 4; ++j) {
        int c = wr * 64 + mi * 16 + (l >> 4) * 4 + j;
        int hh = wc * 64 + ni * 16 + (l & 15);
        part[((size_t)s * KK + c) * HH + ht * 128 + hh] = f2bf(acc[mi][ni][j]);
      }
}

// ---- fused fin+norm: v = (sum_s part)/cluster_r; mub = normalize(v); mubT (last iter) = v; cr=0
__global__ void finorm_kernel(const unsigned short* __restrict__ part,
                              float* __restrict__ cluster_r,
                              unsigned short* __restrict__ mub,
                              unsigned short* __restrict__ mubT, int write_mubT) {
  int c = blockIdx.x, t = threadIdx.x;
  float inv = 1.0f / cluster_r[c];
  float s0 = 0.f, s1 = 0.f;
  const unsigned short* pb = part + (size_t)c * HH;
#pragma unroll 4
  for (int s2 = 0; s2 < NSPLIT; ++s2) {
    s0 += bf2f(pb[(size_t)s2 * KK * HH + t]);
    s1 += bf2f(pb[(size_t)s2 * KK * HH + t + 256]);
  }
  float v0 = s0 * inv, v1 = s1 * inv;
  if (write_mubT) {
    mubT[(size_t)t * KK + c] = f2bf(v0);
    mubT[(size_t)(t + 256) * KK + c] = f2bf(v1);
  }
  float ss = v0 * v0 + v1 * v1;
  ss = wave_reduce_sum(ss);
  __shared__ float red[4];
  if ((t & 63) == 0) red[t >> 6] = ss;
  __syncthreads();
  float rn = 1.0f / sqrtf(red[0] + red[1] + red[2] + red[3]);
  mub[c * HH + t] = f2bf(v0 * rn);
  mub[c * HH + t + 256] = f2bf(v1 * rn);
  if (t == 0) cluster_r[c] = 0.f;
}

// ---- MFMA loss: cs = sigmoid(r@mu) via MFMA; sigma -> LDS; vectorized row-dot phase.
__launch_bounds__(512, 4)
__global__ void loss_mfma(const unsigned short* __restrict__ rbf,
                          const unsigned short* __restrict__ mubT,
                          const unsigned short* __restrict__ posb,
                          const float* __restrict__ neg,
                          const float* __restrict__ inv_norm,
                          const float* __restrict__ Wsv, float* __restrict__ loss_accum) {
  __shared__ __align__(16) unsigned short rS[128 * 128];   // 32KB [i][k] swizzled
  __shared__ __align__(16) unsigned short BsU[128 * 136];  // MFMA B (swizzled) / csS [row][136]
  __shared__ float WsS[HH];
  __shared__ float pcS[128], ncS[128], pgS[128], ngS[128];
  int t = threadIdx.x;
  int w = t >> 6, l = t & 63;
  int wr = w >> 1, wc = w & 1;
  int i0 = blockIdx.x * 128;

  {
    const char* gb = (const char*)rbf + (size_t)i0 * KK * 2;
#pragma unroll
    for (int j = 0; j < 4; ++j) {
      int v = w * 4 + j;
      int row = v * 4 + (l >> 4);
      int cb = ((l & 15) * 16) ^ ((row & 7) << 4);
      gload16(gb + (size_t)row * 256 + cb, (char*)rS + v * 1024);
    }
  }
  WsS[t] = Wsv[t];
  if (t < 128) {
    pcS[t] = 0.f; ncS[t] = 0.f; pgS[t] = 0.f; ngS[t] = 0.f;
  }

  for (int p = 0; p < 4; ++p) {
    __syncthreads();  // (a) prev dot done with csS; p=0: init; barrier drains vmcnt
    {
      const char* gb = (const char*)mubT + (size_t)p * 128 * 256;
#pragma unroll
      for (int j = 0; j < 4; ++j) {
        int v = w * 4 + j;
        int row = v * 4 + (l >> 4);
        int cb = ((l & 15) * 16) ^ ((row & 7) << 4);
        gload16(gb + (size_t)row * 256 + cb, (char*)BsU + v * 1024);
      }
    }
    __syncthreads();  // (b) BsU ready

    float4v acc[2][4];
#pragma unroll
    for (int mi = 0; mi < 2; ++mi)
#pragma unroll
      for (int ni = 0; ni < 4; ++ni) acc[mi][ni] = (float4v){0.f, 0.f, 0.f, 0.f};

#pragma unroll
    for (int ks = 0; ks < 4; ++ks) {
      short8v af[2], bfr[4];
      int kb = ks * 64 + (l >> 4) * 16;
#pragma unroll
      for (int mi = 0; mi < 2; ++mi) {
        int row = wr * 32 + mi * 16 + (l & 15);
        af[mi] = *(const short8v*)((const char*)rS + row * 256 + (kb ^ ((row & 7) << 4)));
      }
#pragma unroll
      for (int ni = 0; ni < 4; ++ni) {
        int hrow = wc * 64 + ni * 16 + (l & 15);
        bfr[ni] = *(const short8v*)((const char*)BsU + hrow * 256 + (kb ^ ((hrow & 7) << 4)));
      }
#pragma unroll
      for (int mi = 0; mi < 2; ++mi)
#pragma unroll
        for (int ni = 0; ni < 4; ++ni)
          acc[mi][ni] = __builtin_amdgcn_mfma_f32_16x16x32_bf16(af[mi], bfr[ni], acc[mi][ni], 0, 0, 0);
    }
    __syncthreads();  // (c) all MFMA reads of BsU done

    unsigned short* csS = BsU;
#pragma unroll
    for (int mi = 0; mi < 2; ++mi)
#pragma unroll
      for (int ni = 0; ni < 4; ++ni)
#pragma unroll
        for (int j = 0; j < 4; ++j) {
          int row = wr * 32 + mi * 16 + (l >> 4) * 4 + j;
          int col = wc * 64 + ni * 16 + (l & 15);
          csS[row * 136 + col] = f2bf(1.0f / (1.0f + __expf(-acc[mi][ni][j])));
        }
    __syncthreads();  // (d) csS ready

    {
      int rl = t >> 2;  // 0..127
      int q = t & 3;
      int gi = i0 + rl;
      bool valid = gi < NN;
      float pc = 0.f, nc = 0.f, pg = 0.f, ng = 0.f;
      const unsigned short* pr = posb + (size_t)gi * HH + p * 128;
      const float* nr = neg + (size_t)gi * HH + p * 128;
      const unsigned short* cr = csS + rl * 136;
#pragma unroll
      for (int e = 0; e < 4; ++e) {
        int cb = e * 32 + q * 8;
        short8v cs8 = *(const short8v*)(cr + cb);
        if (valid) {
          short8v pv8 = *(const short8v*)(pr + cb);
          float4 nv0 = *(const float4*)(nr + cb);
          float4 nv1 = *(const float4*)(nr + cb + 4);
#pragma unroll
          for (int u = 0; u < 8; ++u) {
            float sg = bf2f((unsigned short)cs8[u]);
            float pv = bf2f((unsigned short)pv8[u]);
            float nv = (u < 4) ? (&nv0.x)[u] : (&nv1.x)[u - 4];
            float wv = WsS[p * 128 + cb + u];
            pc = fmaf(sg, pv, pc);
            nc = fmaf(sg, nv, nc);
            pg = fmaf(wv, pv, pg);
            ng = fmaf(wv, nv, ng);
          }
        }
      }
      pc += __shfl_xor(pc, 1); pc += __shfl_xor(pc, 2);
      nc += __shfl_xor(nc, 1); nc += __shfl_xor(nc, 2);
      pg += __shfl_xor(pg, 1); pg += __shfl_xor(pg, 2);
      ng += __shfl_xor(ng, 1); ng += __shfl_xor(ng, 2);
      if (q == 0) {
        pcS[rl] += pc;
        ncS[rl] += nc;
        pgS[rl] += pg;
        ngS[rl] += ng;
      }
    }
  }
  __syncthreads();
  if (t < 128) {
    int gi = i0 + t;
    float contrib = 0.f;
    if (gi < NN) {
      float nrm = 1.0f / inv_norm[gi];  // ||pos||+eps: exact un-normalization
      float pg = pgS[t] * nrm;
      float pc = pcS[t] * nrm;
      float ng = ngS[t];
      float nc = ncS[t];
      contrib = 0.5f * (softplusf(-pg) + softplusf(ng)) +
                0.5f * (softplusf(-pc) + softplusf(nc));
    }
    contrib = wave_reduce_sum(contrib);
    if (l == 0) atomicAdd(loss_accum, contrib);
  }
}

__global__ void out_kernel(const float* __restrict__ loss_accum, float* __restrict__ out) {
  out[0] = loss_accum[0] * (1.0f / NN);
}

extern "C" void kernel_launch(void* const* d_in, const int* in_sizes, int n_in,
                              void* d_out, int out_size, void* d_ws, size_t ws_size,
                              hipStream_t stream) {
  const float* pos = (const float*)d_in[0];
  const float* neg = (const float*)d_in[1];
  const float* init = (const float*)d_in[2];
  const float* W = (const float*)d_in[3];
  float* out = (float*)d_out;

  char* ws = (char*)d_ws;
  size_t off = 0;
  auto alloc = [&](size_t bytes) {
    void* p = ws + off;
    off = (off + bytes + 255) & ~(size_t)255;
    return p;
  };
  unsigned short* posb = (unsigned short*)alloc((size_t)PADN * HH * 2);   // 102.5 MB
  unsigned short* posbT = (unsigned short*)alloc((size_t)HH * PADN * 2);  // 102.5 MB
  unsigned short* rbf = (unsigned short*)alloc((size_t)PADN * KK * 2);    // 25.6 MB
  unsigned short* rbfT = (unsigned short*)alloc((size_t)KK * PADN * 2);   // 25.6 MB
  unsigned short* part = (unsigned short*)alloc((size_t)NSPLIT * KK * HH * 2);  // 16.8 MB
  float* inv_norm = (float*)alloc((size_t)NN * 4);
  unsigned short* mub = (unsigned short*)alloc((size_t)KK * HH * 2);
  unsigned short* mubT = (unsigned short*)alloc((size_t)KK * HH * 2);
  float* cluster_r = (float*)alloc(KK * 4);
  float* colsum = (float*)alloc(HH * 4);
  float* gs = (float*)alloc(HH * 4);
  float* Ws = (float*)alloc(HH * 4);
  float* loss_accum = (float*)alloc(16);

  hipMemsetAsync(colsum, 0, HH * sizeof(float), stream);
  hipMemsetAsync(loss_accum, 0, sizeof(float), stream);

  prep_kernel<<<256, 256, 0, stream>>>(pos, inv_norm, colsum, posb);
  transpose_kernel<<<dim3(PADN / 64, HH / 64), 256, 0, stream>>>(posb, posbT);
  gs_kernel<<<1, 512, 0, stream>>>(colsum, gs);
  wsum_kernel<<<128, 256, 0, stream>>>(W, gs, Ws);

  norm_mu_kernel<<<KK, 256, 0, stream>>>(init, mub, cluster_r);
  for (int it = 0; it < ITERS; ++it) {
    dist_mfma<<<NBLK64, 256, 0, stream>>>(posb, mub, rbf, rbfT, cluster_r, it == ITERS - 1 ? 1 : 0);
    muup_mfma<<<dim3(4, NSPLIT), 256, 0, stream>>>(rbfT, posbT, part);
    finorm_kernel<<<KK, 256, 0, stream>>>(part, cluster_r, mub, mubT, it == ITERS - 1 ? 1 : 0);
  }

  loss_mfma<<<NBLK128, 512, 0, stream>>>(rbf, mubT, posb, neg, inv_norm, Ws, loss_accum);
  out_kernel<<<1, 1, 0, stream>>>(loss_accum, out);
}

// Round 8
// 1239.591 us; speedup vs baseline: 1.4765x; 1.4765x over previous
//
#include <hip/hip_runtime.h>
#include <math.h>

#define NN 100000
#define PADN 100096    // 782*128
#define NBLK128 782
#define HH 512
#define KK 128
#define BETA 100.0f
#define EPSF 1e-8f
#define ITERS 11
#define NSPLIT 128
#define NCHUNK (PADN / 64)  // 1564

typedef __attribute__((ext_vector_type(8))) short short8v;
typedef __attribute__((ext_vector_type(4))) float float4v;

typedef const __attribute__((address_space(1))) void* gas_t;
typedef __attribute__((address_space(3))) void* las_t;

__device__ __forceinline__ void gload16(const void* g, void* l) {
  __builtin_amdgcn_global_load_lds((gas_t)g, (las_t)l, 16, 0, 0);
}

__device__ __forceinline__ unsigned short f2bf(float x) {
  unsigned int u = __float_as_uint(x);
  unsigned int r = (u + 0x7fff + ((u >> 16) & 1)) >> 16;
  return (unsigned short)r;
}
__device__ __forceinline__ float bf2f(unsigned short b) {
  return __uint_as_float((unsigned int)b << 16);
}

__device__ __forceinline__ float wave_reduce_sum(float v) {
#pragma unroll
  for (int off = 32; off > 0; off >>= 1) v += __shfl_xor(v, off);
  return v;
}
__device__ __forceinline__ float softplusf(float x) {
  return fmaxf(x, 0.0f) + log1pf(expf(-fabsf(x)));
}

// ---- fused prep: inv_norm, colsum, posb (normalized bf16), pad-zero
__global__ void prep_kernel(const float* __restrict__ pos,
                            float* __restrict__ inv_norm,
                            float* __restrict__ colsum,
                            unsigned short* __restrict__ posb) {
  int t = threadIdx.x;
  int w = t >> 6, lane = t & 63;
  int gw = blockIdx.x * 4 + w;
  float cpart[8] = {0, 0, 0, 0, 0, 0, 0, 0};
  for (int row = gw; row < NN; row += 1024) {
    const float* p = pos + (size_t)row * HH + lane * 8;
    float4 f0 = *(const float4*)p;
    float4 f1 = *(const float4*)(p + 4);
    float v[8] = {f0.x, f0.y, f0.z, f0.w, f1.x, f1.y, f1.z, f1.w};
    float ss = 0.f;
#pragma unroll
    for (int u = 0; u < 8; ++u) {
      ss += v[u] * v[u];
      cpart[u] += v[u];
    }
    ss = wave_reduce_sum(ss);
    float inv = 1.0f / (sqrtf(ss) + EPSF);
    if (lane == 0) inv_norm[row] = inv;
    short8v o;
#pragma unroll
    for (int u = 0; u < 8; ++u) o[u] = (short)f2bf(v[u] * inv);
    *(short8v*)&posb[(size_t)row * HH + lane * 8] = o;
  }
  {
    int idx = blockIdx.x * 256 + t;
    if (idx < (PADN - NN) * HH / 8) {
      short8v z = (short8v){0, 0, 0, 0, 0, 0, 0, 0};
      *(short8v*)&posb[(size_t)NN * HH + idx * 8] = z;
    }
  }
  __shared__ float cs[HH];
  cs[t] = 0.f;
  cs[t + 256] = 0.f;
  __syncthreads();
#pragma unroll
  for (int u = 0; u < 8; ++u) atomicAdd(&cs[lane * 8 + u], cpart[u]);
  __syncthreads();
  atomicAdd(&colsum[t], cs[t]);
  atomicAdd(&colsum[t + 256], cs[t + 256]);
}

// ---- bf16 transpose posb -> posbT (posb is L3-hot)
__launch_bounds__(256)
__global__ void transpose_kernel(const unsigned short* __restrict__ posb,
                                 unsigned short* __restrict__ posbT) {
  __shared__ unsigned short tile[64][72];
  int t = threadIdx.x;
  int i0 = blockIdx.x * 64, h0 = blockIdx.y * 64;
  int r = t >> 2, cq = (t & 3) * 16;
#pragma unroll
  for (int q = 0; q < 2; ++q) {
    short8v v = *(const short8v*)&posb[(size_t)(i0 + r) * HH + h0 + cq + q * 8];
#pragma unroll
    for (int e = 0; e < 8; ++e) tile[cq + q * 8 + e][r] = (unsigned short)v[e];
  }
  __syncthreads();
  int h = t >> 2, iq = (t & 3) * 16;
#pragma unroll
  for (int q = 0; q < 2; ++q)
    *(short8v*)&posbT[(size_t)(h0 + h) * PADN + i0 + iq + q * 8] =
        *(const short8v*)&tile[h][iq + q * 8];
}

// ---- gs[h] = sigmoid(colsum[h]/N)
__global__ void gs_kernel(const float* __restrict__ colsum, float* __restrict__ gs) {
  int t = threadIdx.x;
  float m = colsum[t] * (1.0f / NN);
  gs[t] = 1.0f / (1.0f + expf(-m));
}

// ---- Ws[j] = sum_h W[j][h]*gs[h]
__global__ void wsum_kernel(const float* __restrict__ W, const float* __restrict__ gs,
                            float* __restrict__ Ws) {
  int w = threadIdx.x >> 6, lane = threadIdx.x & 63;
  int row = blockIdx.x * 4 + w;
  const float* Wr = W + (size_t)row * HH;
  float s = 0.f;
#pragma unroll
  for (int j = 0; j < 8; ++j) s += Wr[lane + 64 * j] * gs[lane + 64 * j];
  s = wave_reduce_sum(s);
  if (lane == 0) Ws[row] = s;
}

// ---- mub (bf16) = row / ||row|| from fp32 src. Used once on init.
__global__ void norm_mu_kernel(const float* __restrict__ src, unsigned short* __restrict__ mub) {
  int k = blockIdx.x, t = threadIdx.x;
  float v0 = src[k * HH + t], v1 = src[k * HH + t + 256];
  float ss = v0 * v0 + v1 * v1;
  ss = wave_reduce_sum(ss);
  __shared__ float red[4];
  if ((t & 63) == 0) red[t >> 6] = ss;
  __syncthreads();
  float inv = 1.0f / sqrtf(red[0] + red[1] + red[2] + red[3]);
  mub[k * HH + t] = f2bf(v0 * inv);
  mub[k * HH + t + 256] = f2bf(v1 * inv);
}

// ---- MFMA dist + fused softmax. BM=128, 256 thr, 4x4 acc, swizzled A/B dbuf.
// T4: counted vmcnt + raw s_barrier keeps prefetch loads in flight across barriers.
__launch_bounds__(256, 2)
__global__ void dist_mfma(const unsigned short* __restrict__ posb,
                          const unsigned short* __restrict__ mub,
                          unsigned short* __restrict__ rbf,
                          unsigned short* __restrict__ rbfT,
                          int write_rbf) {
  __shared__ __align__(16) unsigned short smem[32768];  // 64KB: As[2][8192] | Bs[2][8192]
  unsigned short* As0 = smem;
  unsigned short* Bs0 = smem + 16384;
  unsigned short* rT = smem;  // [128 c][136] epilogue alias
  __shared__ float redM[2][128];
  __shared__ float redS[2][128];

  int t = threadIdx.x;
  int w = t >> 6, l = t & 63;
  int wr = w >> 1, wc = w & 1;
  int i0 = blockIdx.x * 128;

  float4v acc[4][4];
#pragma unroll
  for (int mi = 0; mi < 4; ++mi)
#pragma unroll
    for (int ni = 0; ni < 4; ++ni) acc[mi][ni] = (float4v){0.f, 0.f, 0.f, 0.f};

  int rsub = l >> 3;
  int scol = ((l & 7) ^ rsub) * 8;  // shorts

  auto stage = [&](int buf, int ch) {
    int h0 = ch * 64;
#pragma unroll
    for (int j = 0; j < 4; ++j) {
      int v = w * 4 + j;
      int row = v * 8 + rsub;
      gload16(posb + (size_t)(i0 + row) * HH + h0 + scol, As0 + buf * 8192 + v * 512);
      gload16(mub + (size_t)row * HH + h0 + scol, Bs0 + buf * 8192 + v * 512);
    }
  };

  stage(0, 0);  // 8 loads in flight
  int cur = 0;
  for (int ch = 0; ch < 8; ++ch) {
    if (ch < 7) {
      stage(cur ^ 1, ch + 1);  // +8 loads (16 outstanding)
      asm volatile("s_waitcnt vmcnt(8)" ::: "memory");  // wait cur's 8; prefetch stays in flight
    } else {
      asm volatile("s_waitcnt vmcnt(0)" ::: "memory");
    }
    __builtin_amdgcn_s_barrier();
    __builtin_amdgcn_sched_barrier(0);
    const char* ab = (const char*)(As0 + cur * 8192);
    const char* bb = (const char*)(Bs0 + cur * 8192);
#pragma unroll
    for (int ks = 0; ks < 2; ++ks) {
      short8v af[4], bfr[4];
      int kb = ks * 64 + (l >> 4) * 16;
      int rx = ((l & 7) << 4);
#pragma unroll
      for (int mi = 0; mi < 4; ++mi) {
        int row = wr * 64 + mi * 16 + (l & 15);
        af[mi] = *(const short8v*)(ab + row * 128 + (kb ^ rx));
      }
#pragma unroll
      for (int ni = 0; ni < 4; ++ni) {
        int row = wc * 64 + ni * 16 + (l & 15);
        bfr[ni] = *(const short8v*)(bb + row * 128 + (kb ^ rx));
      }
#pragma unroll
      for (int mi = 0; mi < 4; ++mi)
#pragma unroll
        for (int ni = 0; ni < 4; ++ni)
          acc[mi][ni] = __builtin_amdgcn_mfma_f32_16x16x32_bf16(af[mi], bfr[ni], acc[mi][ni], 0, 0, 0);
    }
    __builtin_amdgcn_sched_barrier(0);  // no motion of next stage above this point
    __builtin_amdgcn_s_barrier();       // all waves done reading cur before it is restaged
    __builtin_amdgcn_sched_barrier(0);
    cur ^= 1;
  }

  // ---- softmax epilogue. row(local) = wr*64+mi*16+(l>>4)*4+j, col = wc*64+ni*16+(l&15)
  float wmax[4][4];
#pragma unroll
  for (int mi = 0; mi < 4; ++mi)
#pragma unroll
    for (int j = 0; j < 4; ++j) {
      float m = fmaxf(fmaxf(acc[mi][0][j], acc[mi][1][j]), fmaxf(acc[mi][2][j], acc[mi][3][j])) * BETA;
      m = fmaxf(m, __shfl_xor(m, 1));
      m = fmaxf(m, __shfl_xor(m, 2));
      m = fmaxf(m, __shfl_xor(m, 4));
      m = fmaxf(m, __shfl_xor(m, 8));
      wmax[mi][j] = m;
    }
  if ((l & 15) == 0) {
#pragma unroll
    for (int mi = 0; mi < 4; ++mi)
#pragma unroll
      for (int j = 0; j < 4; ++j)
        redM[wc][wr * 64 + mi * 16 + (l >> 4) * 4 + j] = wmax[mi][j];
  }
  __syncthreads();
  float fm[4][4];
#pragma unroll
  for (int mi = 0; mi < 4; ++mi)
#pragma unroll
    for (int j = 0; j < 4; ++j) {
      int row = wr * 64 + mi * 16 + (l >> 4) * 4 + j;
      fm[mi][j] = fmaxf(redM[0][row], redM[1][row]);
    }
#pragma unroll
  for (int mi = 0; mi < 4; ++mi)
#pragma unroll
    for (int j = 0; j < 4; ++j) {
      float s = 0.f;
#pragma unroll
      for (int ni = 0; ni < 4; ++ni) {
        float e = __expf(acc[mi][ni][j] * BETA - fm[mi][j]);
        acc[mi][ni][j] = e;
        s += e;
      }
      s += __shfl_xor(s, 1);
      s += __shfl_xor(s, 2);
      s += __shfl_xor(s, 4);
      s += __shfl_xor(s, 8);
      wmax[mi][j] = s;  // reuse
    }
  if ((l & 15) == 0) {
#pragma unroll
    for (int mi = 0; mi < 4; ++mi)
#pragma unroll
      for (int j = 0; j < 4; ++j)
        redS[wc][wr * 64 + mi * 16 + (l >> 4) * 4 + j] = wmax[mi][j];
  }
  __syncthreads();

#pragma unroll
  for (int mi = 0; mi < 4; ++mi)
#pragma unroll
    for (int j = 0; j < 4; ++j) {
      int row = wr * 64 + mi * 16 + (l >> 4) * 4 + j;
      float invs = 1.0f / (redS[0][row] + redS[1][row]);
#pragma unroll
      for (int ni = 0; ni < 4; ++ni) {
        float rv = acc[mi][ni][j] * invs;
        rT[(wc * 64 + ni * 16 + (l & 15)) * 136 + row] = f2bf(rv);
      }
    }
  __syncthreads();

  {
    int c = t >> 1, half = t & 1;
    const unsigned short* src = &rT[c * 136 + half * 64];
    unsigned short* dst = &rbfT[(size_t)c * PADN + i0 + half * 64];
#pragma unroll
    for (int q = 0; q < 8; ++q)
      *(short8v*)(dst + q * 8) = *(const short8v*)(src + q * 8);
  }
  if (write_rbf) {
    int i = t >> 1, chalf = t & 1;
#pragma unroll
    for (int q = 0; q < 8; ++q) {
      short8v v;
#pragma unroll
      for (int e = 0; e < 8; ++e) v[e] = (short)rT[(chalf * 64 + q * 8 + e) * 136 + i];
      *(short8v*)&rbf[(size_t)(i0 + i) * KK + chalf * 64 + q * 8] = v;
    }
  }
}

// ---- cluster_r partials: crpart[c*8+p] = sum over part p's i-range of rbfT[c][i]
__launch_bounds__(256)
__global__ void crsum_kernel(const unsigned short* __restrict__ rbfT,
                             float* __restrict__ crpart) {
  int c = blockIdx.x, p = blockIdx.y, t = threadIdx.x;
  const unsigned short* row = rbfT + (size_t)c * PADN;
  int base = p * 12512;
  int end = base + 12512;
  if (end > NN) end = NN;
  float s = 0.f;
  for (int i = base + t * 8; i < end; i += 2048) {
    short8v v = *(const short8v*)(row + i);
#pragma unroll
    for (int u = 0; u < 8; ++u) s += bf2f((unsigned short)v[u]);
  }
  s = wave_reduce_sum(s);
  __shared__ float red[4];
  if ((t & 63) == 0) red[t >> 6] = s;
  __syncthreads();
  if (t == 0) crpart[c * 8 + p] = red[0] + red[1] + red[2] + red[3];
}

// ---- MFMA mu update. A (rbfT) + B (posbT) LDS double-buffered, XOR-swizzled.
__launch_bounds__(256, 2)
__global__ void muup_mfma(const unsigned short* __restrict__ rbfT,
                          const unsigned short* __restrict__ posbT,
                          unsigned short* __restrict__ part) {
  __shared__ __align__(16) unsigned short smem[32768];  // As[2][8192] | Bs[2][8192]
  unsigned short* As0 = smem;
  unsigned short* Bs0 = smem + 16384;
  int t = threadIdx.x;
  int w = t >> 6, l = t & 63;
  int wr = w >> 1, wc = w & 1;
  int ht = blockIdx.x, s = blockIdx.y;

  float4v acc[4][4];
#pragma unroll
  for (int mi = 0; mi < 4; ++mi)
#pragma unroll
    for (int ni = 0; ni < 4; ++ni) acc[mi][ni] = (float4v){0.f, 0.f, 0.f, 0.f};

  int rsub = l >> 3;
  int scol = ((l & 7) ^ rsub) * 8;  // shorts

  auto stage = [&](int buf, int ch) {
    size_t ib = (size_t)ch * 64;
#pragma unroll
    for (int j = 0; j < 4; ++j) {
      int v = w * 4 + j;
      int row = v * 8 + rsub;
      gload16(rbfT + (size_t)row * PADN + ib + scol, As0 + buf * 8192 + v * 512);
      gload16(posbT + (size_t)(ht * 128 + row) * PADN + ib + scol, Bs0 + buf * 8192 + v * 512);
    }
  };

  int ch = s;
  stage(0, ch);
  __syncthreads();
  int cur = 0;
  for (; ch < NCHUNK; ch += NSPLIT) {
    int nxt = ch + NSPLIT;
    if (nxt < NCHUNK) stage(cur ^ 1, nxt);
    const char* ab = (const char*)(As0 + cur * 8192);
    const char* bb = (const char*)(Bs0 + cur * 8192);
#pragma unroll
    for (int ks = 0; ks < 2; ++ks) {
      short8v af[4], bfr[4];
      int kb = ks * 64 + (l >> 4) * 16;
      int rx = ((l & 7) << 4);
#pragma unroll
      for (int mi = 0; mi < 4; ++mi) {
        int row = wr * 64 + mi * 16 + (l & 15);
        af[mi] = *(const short8v*)(ab + row * 128 + (kb ^ rx));
      }
#pragma unroll
      for (int ni = 0; ni < 4; ++ni) {
        int row = wc * 64 + ni * 16 + (l & 15);
        bfr[ni] = *(const short8v*)(bb + row * 128 + (kb ^ rx));
      }
#pragma unroll
      for (int mi = 0; mi < 4; ++mi)
#pragma unroll
        for (int ni = 0; ni < 4; ++ni)
          acc[mi][ni] = __builtin_amdgcn_mfma_f32_16x16x32_bf16(af[mi], bfr[ni], acc[mi][ni], 0, 0, 0);
    }
    __syncthreads();
    cur ^= 1;
  }
#pragma unroll
  for (int mi = 0; mi < 4; ++mi)
#pragma unroll
    for (int ni = 0; ni < 4; ++ni)
#pragma unroll
      for (int j = 0; j < 4; ++j) {
        int c = wr * 64 + mi * 16 + (l >> 4) * 4 + j;
        int hh = wc * 64 + ni * 16 + (l & 15);
        part[((size_t)s * KK + c) * HH + ht * 128 + hh] = f2bf(acc[mi][ni][j]);
      }
}

// ---- fused fin+norm: v = (sum_s part)/cr; mub = normalize(v); mubT (last iter) = v
__global__ void finorm_kernel(const unsigned short* __restrict__ part,
                              const float* __restrict__ crpart,
                              unsigned short* __restrict__ mub,
                              unsigned short* __restrict__ mubT, int write_mubT) {
  int c = blockIdx.x, t = threadIdx.x;
  float cr = 0.f;
#pragma unroll
  for (int p = 0; p < 8; ++p) cr += crpart[c * 8 + p];
  float inv = 1.0f / cr;
  float s0 = 0.f, s1 = 0.f;
  const unsigned short* pb = part + (size_t)c * HH;
#pragma unroll 4
  for (int s2 = 0; s2 < NSPLIT; ++s2) {
    s0 += bf2f(pb[(size_t)s2 * KK * HH + t]);
    s1 += bf2f(pb[(size_t)s2 * KK * HH + t + 256]);
  }
  float v0 = s0 * inv, v1 = s1 * inv;
  if (write_mubT) {
    mubT[(size_t)t * KK + c] = f2bf(v0);
    mubT[(size_t)(t + 256) * KK + c] = f2bf(v1);
  }
  float ss = v0 * v0 + v1 * v1;
  ss = wave_reduce_sum(ss);
  __shared__ float red[4];
  if ((t & 63) == 0) red[t >> 6] = ss;
  __syncthreads();
  float rn = 1.0f / sqrtf(red[0] + red[1] + red[2] + red[3]);
  mub[c * HH + t] = f2bf(v0 * rn);
  mub[c * HH + t + 256] = f2bf(v1 * rn);
}

// ---- MFMA loss: cs = sigmoid(r@mu) via MFMA; sigma -> LDS; vectorized row-dot phase.
__launch_bounds__(512, 4)
__global__ void loss_mfma(const unsigned short* __restrict__ rbf,
                          const unsigned short* __restrict__ mubT,
                          const unsigned short* __restrict__ posb,
                          const float* __restrict__ neg,
                          const float* __restrict__ inv_norm,
                          const float* __restrict__ Wsv, float* __restrict__ loss_accum) {
  __shared__ __align__(16) unsigned short rS[128 * 128];   // 32KB [i][k] swizzled
  __shared__ __align__(16) unsigned short BsU[128 * 136];  // MFMA B (swizzled) / csS [row][136]
  __shared__ float WsS[HH];
  __shared__ float pcS[128], ncS[128], pgS[128], ngS[128];
  int t = threadIdx.x;
  int w = t >> 6, l = t & 63;
  int wr = w >> 1, wc = w & 1;
  int i0 = blockIdx.x * 128;

  {
    const char* gb = (const char*)rbf + (size_t)i0 * KK * 2;
#pragma unroll
    for (int j = 0; j < 4; ++j) {
      int v = w * 4 + j;
      int row = v * 4 + (l >> 4);
      int cb = ((l & 15) * 16) ^ ((row & 7) << 4);
      gload16(gb + (size_t)row * 256 + cb, (char*)rS + v * 1024);
    }
  }
  WsS[t] = Wsv[t];
  if (t < 128) {
    pcS[t] = 0.f; ncS[t] = 0.f; pgS[t] = 0.f; ngS[t] = 0.f;
  }

  for (int p = 0; p < 4; ++p) {
    __syncthreads();  // (a) prev dot done with csS; p=0: init; barrier drains vmcnt
    {
      const char* gb = (const char*)mubT + (size_t)p * 128 * 256;
#pragma unroll
      for (int j = 0; j < 4; ++j) {
        int v = w * 4 + j;
        int row = v * 4 + (l >> 4);
        int cb = ((l & 15) * 16) ^ ((row & 7) << 4);
        gload16(gb + (size_t)row * 256 + cb, (char*)BsU + v * 1024);
      }
    }
    __syncthreads();  // (b) BsU ready

    float4v acc[2][4];
#pragma unroll
    for (int mi = 0; mi < 2; ++mi)
#pragma unroll
      for (int ni = 0; ni < 4; ++ni) acc[mi][ni] = (float4v){0.f, 0.f, 0.f, 0.f};

#pragma unroll
    for (int ks = 0; ks < 4; ++ks) {
      short8v af[2], bfr[4];
      int kb = ks * 64 + (l >> 4) * 16;
#pragma unroll
      for (int mi = 0; mi < 2; ++mi) {
        int row = wr * 32 + mi * 16 + (l & 15);
        af[mi] = *(const short8v*)((const char*)rS + row * 256 + (kb ^ ((row & 7) << 4)));
      }
#pragma unroll
      for (int ni = 0; ni < 4; ++ni) {
        int hrow = wc * 64 + ni * 16 + (l & 15);
        bfr[ni] = *(const short8v*)((const char*)BsU + hrow * 256 + (kb ^ ((hrow & 7) << 4)));
      }
#pragma unroll
      for (int mi = 0; mi < 2; ++mi)
#pragma unroll
        for (int ni = 0; ni < 4; ++ni)
          acc[mi][ni] = __builtin_amdgcn_mfma_f32_16x16x32_bf16(af[mi], bfr[ni], acc[mi][ni], 0, 0, 0);
    }
    __syncthreads();  // (c) all MFMA reads of BsU done

    unsigned short* csS = BsU;
#pragma unroll
    for (int mi = 0; mi < 2; ++mi)
#pragma unroll
      for (int ni = 0; ni < 4; ++ni)
#pragma unroll
        for (int j = 0; j < 4; ++j) {
          int row = wr * 32 + mi * 16 + (l >> 4) * 4 + j;
          int col = wc * 64 + ni * 16 + (l & 15);
          csS[row * 136 + col] = f2bf(1.0f / (1.0f + __expf(-acc[mi][ni][j])));
        }
    __syncthreads();  // (d) csS ready

    {
      int rl = t >> 2;  // 0..127
      int q = t & 3;
      int gi = i0 + rl;
      bool valid = gi < NN;
      float pc = 0.f, nc = 0.f, pg = 0.f, ng = 0.f;
      const unsigned short* pr = posb + (size_t)gi * HH + p * 128;
      const float* nr = neg + (size_t)gi * HH + p * 128;
      const unsigned short* cr = csS + rl * 136;
#pragma unroll
      for (int e = 0; e < 4; ++e) {
        int cb = e * 32 + q * 8;
        short8v cs8 = *(const short8v*)(cr + cb);
        if (valid) {
          short8v pv8 = *(const short8v*)(pr + cb);
          float4 nv0 = *(const float4*)(nr + cb);
          float4 nv1 = *(const float4*)(nr + cb + 4);
#pragma unroll
          for (int u = 0; u < 8; ++u) {
            float sg = bf2f((unsigned short)cs8[u]);
            float pv = bf2f((unsigned short)pv8[u]);
            float nv = (u < 4) ? (&nv0.x)[u] : (&nv1.x)[u - 4];
            float wv = WsS[p * 128 + cb + u];
            pc = fmaf(sg, pv, pc);
            nc = fmaf(sg, nv, nc);
            pg = fmaf(wv, pv, pg);
            ng = fmaf(wv, nv, ng);
          }
        }
      }
      pc += __shfl_xor(pc, 1); pc += __shfl_xor(pc, 2);
      nc += __shfl_xor(nc, 1); nc += __shfl_xor(nc, 2);
      pg += __shfl_xor(pg, 1); pg += __shfl_xor(pg, 2);
      ng += __shfl_xor(ng, 1); ng += __shfl_xor(ng, 2);
      if (q == 0) {
        pcS[rl] += pc;
        ncS[rl] += nc;
        pgS[rl] += pg;
        ngS[rl] += ng;
      }
    }
  }
  __syncthreads();
  if (t < 128) {
    int gi = i0 + t;
    float contrib = 0.f;
    if (gi < NN) {
      float nrm = 1.0f / inv_norm[gi];  // ||pos||+eps: exact un-normalization
      float pg = pgS[t] * nrm;
      float pc = pcS[t] * nrm;
      float ng = ngS[t];
      float nc = ncS[t];
      contrib = 0.5f * (softplusf(-pg) + softplusf(ng)) +
                0.5f * (softplusf(-pc) + softplusf(nc));
    }
    contrib = wave_reduce_sum(contrib);
    if (l == 0) atomicAdd(loss_accum, contrib);
  }
}

__global__ void out_kernel(const float* __restrict__ loss_accum, float* __restrict__ out) {
  out[0] = loss_accum[0] * (1.0f / NN);
}

extern "C" void kernel_launch(void* const* d_in, const int* in_sizes, int n_in,
                              void* d_out, int out_size, void* d_ws, size_t ws_size,
                              hipStream_t stream) {
  const float* pos = (const float*)d_in[0];
  const float* neg = (const float*)d_in[1];
  const float* init = (const float*)d_in[2];
  const float* W = (const float*)d_in[3];
  float* out = (float*)d_out;

  char* ws = (char*)d_ws;
  size_t off = 0;
  auto alloc = [&](size_t bytes) {
    void* p = ws + off;
    off = (off + bytes + 255) & ~(size_t)255;
    return p;
  };
  unsigned short* posb = (unsigned short*)alloc((size_t)PADN * HH * 2);   // 102.5 MB
  unsigned short* posbT = (unsigned short*)alloc((size_t)HH * PADN * 2);  // 102.5 MB
  unsigned short* rbf = (unsigned short*)alloc((size_t)PADN * KK * 2);    // 25.6 MB
  unsigned short* rbfT = (unsigned short*)alloc((size_t)KK * PADN * 2);   // 25.6 MB
  unsigned short* part = (unsigned short*)alloc((size_t)NSPLIT * KK * HH * 2);  // 16.8 MB
  float* inv_norm = (float*)alloc((size_t)NN * 4);
  unsigned short* mub = (unsigned short*)alloc((size_t)KK * HH * 2);
  unsigned short* mubT = (unsigned short*)alloc((size_t)KK * HH * 2);
  float* crpart = (float*)alloc(KK * 8 * 4);
  float* colsum = (float*)alloc(HH * 4);
  float* gs = (float*)alloc(HH * 4);
  float* Ws = (float*)alloc(HH * 4);
  float* loss_accum = (float*)alloc(16);

  hipMemsetAsync(colsum, 0, HH * sizeof(float), stream);
  hipMemsetAsync(loss_accum, 0, sizeof(float), stream);

  prep_kernel<<<256, 256, 0, stream>>>(pos, inv_norm, colsum, posb);
  transpose_kernel<<<dim3(PADN / 64, HH / 64), 256, 0, stream>>>(posb, posbT);
  gs_kernel<<<1, 512, 0, stream>>>(colsum, gs);
  wsum_kernel<<<128, 256, 0, stream>>>(W, gs, Ws);

  norm_mu_kernel<<<KK, 256, 0, stream>>>(init, mub);
  for (int it = 0; it < ITERS; ++it) {
    dist_mfma<<<NBLK128, 256, 0, stream>>>(posb, mub, rbf, rbfT, it == ITERS - 1 ? 1 : 0);
    crsum_kernel<<<dim3(KK, 8), 256, 0, stream>>>(rbfT, crpart);
    muup_mfma<<<dim3(4, NSPLIT), 256, 0, stream>>>(rbfT, posbT, part);
    finorm_kernel<<<KK, 256, 0, stream>>>(part, crpart, mub, mubT, it == ITERS - 1 ? 1 : 0);
  }

  loss_mfma<<<NBLK128, 512, 0, stream>>>(rbf, mubT, posb, neg, inv_norm, Ws, loss_accum);
  out_kernel<<<1, 1, 0, stream>>>(loss_accum, out);
}

// Round 9
// 1236.144 us; speedup vs baseline: 1.4806x; 1.0028x over previous
//
#include <hip/hip_runtime.h>
#include <math.h>

#define NN 100000
#define PADN 100096    // 782*128
#define NBLK128 782
#define HH 512
#define KK 128
#define BETA 100.0f
#define EPSF 1e-8f
#define ITERS 11
#define NSPLIT 128
#define NCHUNK (PADN / 64)  // 1564
#define PREPB 1024

typedef __attribute__((ext_vector_type(8))) short short8v;
typedef __attribute__((ext_vector_type(4))) float float4v;

typedef const __attribute__((address_space(1))) void* gas_t;
typedef __attribute__((address_space(3))) void* las_t;

__device__ __forceinline__ void gload16(const void* g, void* l) {
  __builtin_amdgcn_global_load_lds((gas_t)g, (las_t)l, 16, 0, 0);
}

__device__ __forceinline__ unsigned short f2bf(float x) {
  unsigned int u = __float_as_uint(x);
  unsigned int r = (u + 0x7fff + ((u >> 16) & 1)) >> 16;
  return (unsigned short)r;
}
__device__ __forceinline__ float bf2f(unsigned short b) {
  return __uint_as_float((unsigned int)b << 16);
}

__device__ __forceinline__ float wave_reduce_sum(float v) {
#pragma unroll
  for (int off = 32; off > 0; off >>= 1) v += __shfl_xor(v, off);
  return v;
}
__device__ __forceinline__ float softplusf(float x) {
  return fmaxf(x, 0.0f) + log1pf(expf(-fabsf(x)));
}

// ---- fused prep: inv_norm, colpart (per-block colsum), posb (normalized bf16), pad-zero
__global__ void prep_kernel(const float* __restrict__ pos,
                            float* __restrict__ inv_norm,
                            float* __restrict__ colpart,
                            unsigned short* __restrict__ posb) {
  int t = threadIdx.x;
  int w = t >> 6, lane = t & 63;
  int gw = blockIdx.x * 4 + w;  // 0..4095
  float cpart[8] = {0, 0, 0, 0, 0, 0, 0, 0};
  for (int row = gw; row < NN; row += PREPB * 4) {
    const float* p = pos + (size_t)row * HH + lane * 8;
    float4 f0 = *(const float4*)p;
    float4 f1 = *(const float4*)(p + 4);
    float v[8] = {f0.x, f0.y, f0.z, f0.w, f1.x, f1.y, f1.z, f1.w};
    float ss = 0.f;
#pragma unroll
    for (int u = 0; u < 8; ++u) {
      ss += v[u] * v[u];
      cpart[u] += v[u];
    }
    ss = wave_reduce_sum(ss);
    float inv = 1.0f / (sqrtf(ss) + EPSF);
    if (lane == 0) inv_norm[row] = inv;
    short8v o;
#pragma unroll
    for (int u = 0; u < 8; ++u) o[u] = (short)f2bf(v[u] * inv);
    *(short8v*)&posb[(size_t)row * HH + lane * 8] = o;
  }
  {
    int idx = blockIdx.x * 256 + t;
    if (idx < (PADN - NN) * HH / 8) {
      short8v z = (short8v){0, 0, 0, 0, 0, 0, 0, 0};
      *(short8v*)&posb[(size_t)NN * HH + idx * 8] = z;
    }
  }
  __shared__ float cs[HH];
  cs[t] = 0.f;
  cs[t + 256] = 0.f;
  __syncthreads();
#pragma unroll
  for (int u = 0; u < 8; ++u) atomicAdd(&cs[lane * 8 + u], cpart[u]);
  __syncthreads();
  colpart[(size_t)blockIdx.x * HH + t] = cs[t];
  colpart[(size_t)blockIdx.x * HH + t + 256] = cs[t + 256];
}

// ---- bf16 transpose posb -> posbT (posb is L3-hot)
__launch_bounds__(256)
__global__ void transpose_kernel(const unsigned short* __restrict__ posb,
                                 unsigned short* __restrict__ posbT) {
  __shared__ unsigned short tile[64][72];
  int t = threadIdx.x;
  int i0 = blockIdx.x * 64, h0 = blockIdx.y * 64;
  int r = t >> 2, cq = (t & 3) * 16;
#pragma unroll
  for (int q = 0; q < 2; ++q) {
    short8v v = *(const short8v*)&posb[(size_t)(i0 + r) * HH + h0 + cq + q * 8];
#pragma unroll
    for (int e = 0; e < 8; ++e) tile[cq + q * 8 + e][r] = (unsigned short)v[e];
  }
  __syncthreads();
  int h = t >> 2, iq = (t & 3) * 16;
#pragma unroll
  for (int q = 0; q < 2; ++q)
    *(short8v*)&posbT[(size_t)(h0 + h) * PADN + i0 + iq + q * 8] =
        *(const short8v*)&tile[h][iq + q * 8];
}

// ---- gs[h] = sigmoid(sum_b colpart[b][h] / N)
__global__ void gs_kernel(const float* __restrict__ colpart, float* __restrict__ gs) {
  int t = threadIdx.x;  // 512
  float s = 0.f;
  for (int b = 0; b < PREPB; ++b) s += colpart[(size_t)b * HH + t];
  float m = s * (1.0f / NN);
  gs[t] = 1.0f / (1.0f + expf(-m));
}

// ---- Ws[j] = sum_h W[j][h]*gs[h]
__global__ void wsum_kernel(const float* __restrict__ W, const float* __restrict__ gs,
                            float* __restrict__ Ws) {
  int w = threadIdx.x >> 6, lane = threadIdx.x & 63;
  int row = blockIdx.x * 4 + w;
  const float* Wr = W + (size_t)row * HH;
  float s = 0.f;
#pragma unroll
  for (int j = 0; j < 8; ++j) s += Wr[lane + 64 * j] * gs[lane + 64 * j];
  s = wave_reduce_sum(s);
  if (lane == 0) Ws[row] = s;
}

// ---- mub (bf16) = row / ||row|| from fp32 src. Used once on init.
__global__ void norm_mu_kernel(const float* __restrict__ src, unsigned short* __restrict__ mub) {
  int k = blockIdx.x, t = threadIdx.x;
  float v0 = src[k * HH + t], v1 = src[k * HH + t + 256];
  float ss = v0 * v0 + v1 * v1;
  ss = wave_reduce_sum(ss);
  __shared__ float red[4];
  if ((t & 63) == 0) red[t >> 6] = ss;
  __syncthreads();
  float inv = 1.0f / sqrtf(red[0] + red[1] + red[2] + red[3]);
  mub[k * HH + t] = f2bf(v0 * inv);
  mub[k * HH + t + 256] = f2bf(v1 * inv);
}

// ---- MFMA dist + fused softmax. BM=128, 256 thr, 4x4 acc, swizzled A/B dbuf.
// T4: counted vmcnt + raw s_barrier keeps prefetch loads in flight across barriers.
__launch_bounds__(256, 2)
__global__ void dist_mfma(const unsigned short* __restrict__ posb,
                          const unsigned short* __restrict__ mub,
                          unsigned short* __restrict__ rbf,
                          unsigned short* __restrict__ rbfT,
                          int write_rbf) {
  __shared__ __align__(16) unsigned short smem[32768];  // 64KB: As[2][8192] | Bs[2][8192]
  unsigned short* As0 = smem;
  unsigned short* Bs0 = smem + 16384;
  unsigned short* rT = smem;  // [128 c][136] epilogue alias
  __shared__ float redM[2][128];
  __shared__ float redS[2][128];

  int t = threadIdx.x;
  int w = t >> 6, l = t & 63;
  int wr = w >> 1, wc = w & 1;
  int i0 = blockIdx.x * 128;

  float4v acc[4][4];
#pragma unroll
  for (int mi = 0; mi < 4; ++mi)
#pragma unroll
    for (int ni = 0; ni < 4; ++ni) acc[mi][ni] = (float4v){0.f, 0.f, 0.f, 0.f};

  int rsub = l >> 3;
  int scol = ((l & 7) ^ rsub) * 8;  // shorts

  auto stage = [&](int buf, int ch) {
    int h0 = ch * 64;
#pragma unroll
    for (int j = 0; j < 4; ++j) {
      int v = w * 4 + j;
      int row = v * 8 + rsub;
      gload16(posb + (size_t)(i0 + row) * HH + h0 + scol, As0 + buf * 8192 + v * 512);
      gload16(mub + (size_t)row * HH + h0 + scol, Bs0 + buf * 8192 + v * 512);
    }
  };

  stage(0, 0);  // 8 loads in flight
  int cur = 0;
  for (int ch = 0; ch < 8; ++ch) {
    if (ch < 7) {
      stage(cur ^ 1, ch + 1);  // +8 loads (16 outstanding)
      asm volatile("s_waitcnt vmcnt(8)" ::: "memory");  // wait cur's 8; prefetch stays in flight
    } else {
      asm volatile("s_waitcnt vmcnt(0)" ::: "memory");
    }
    __builtin_amdgcn_s_barrier();
    __builtin_amdgcn_sched_barrier(0);
    const char* ab = (const char*)(As0 + cur * 8192);
    const char* bb = (const char*)(Bs0 + cur * 8192);
#pragma unroll
    for (int ks = 0; ks < 2; ++ks) {
      short8v af[4], bfr[4];
      int kb = ks * 64 + (l >> 4) * 16;
      int rx = ((l & 7) << 4);
#pragma unroll
      for (int mi = 0; mi < 4; ++mi) {
        int row = wr * 64 + mi * 16 + (l & 15);
        af[mi] = *(const short8v*)(ab + row * 128 + (kb ^ rx));
      }
#pragma unroll
      for (int ni = 0; ni < 4; ++ni) {
        int row = wc * 64 + ni * 16 + (l & 15);
        bfr[ni] = *(const short8v*)(bb + row * 128 + (kb ^ rx));
      }
#pragma unroll
      for (int mi = 0; mi < 4; ++mi)
#pragma unroll
        for (int ni = 0; ni < 4; ++ni)
          acc[mi][ni] = __builtin_amdgcn_mfma_f32_16x16x32_bf16(af[mi], bfr[ni], acc[mi][ni], 0, 0, 0);
    }
    __builtin_amdgcn_sched_barrier(0);  // no motion of next stage above this point
    __builtin_amdgcn_s_barrier();       // all waves done reading cur before it is restaged
    __builtin_amdgcn_sched_barrier(0);
    cur ^= 1;
  }

  // ---- softmax epilogue. row(local) = wr*64+mi*16+(l>>4)*4+j, col = wc*64+ni*16+(l&15)
  float wmax[4][4];
#pragma unroll
  for (int mi = 0; mi < 4; ++mi)
#pragma unroll
    for (int j = 0; j < 4; ++j) {
      float m = fmaxf(fmaxf(acc[mi][0][j], acc[mi][1][j]), fmaxf(acc[mi][2][j], acc[mi][3][j])) * BETA;
      m = fmaxf(m, __shfl_xor(m, 1));
      m = fmaxf(m, __shfl_xor(m, 2));
      m = fmaxf(m, __shfl_xor(m, 4));
      m = fmaxf(m, __shfl_xor(m, 8));
      wmax[mi][j] = m;
    }
  if ((l & 15) == 0) {
#pragma unroll
    for (int mi = 0; mi < 4; ++mi)
#pragma unroll
      for (int j = 0; j < 4; ++j)
        redM[wc][wr * 64 + mi * 16 + (l >> 4) * 4 + j] = wmax[mi][j];
  }
  __syncthreads();
  float fm[4][4];
#pragma unroll
  for (int mi = 0; mi < 4; ++mi)
#pragma unroll
    for (int j = 0; j < 4; ++j) {
      int row = wr * 64 + mi * 16 + (l >> 4) * 4 + j;
      fm[mi][j] = fmaxf(redM[0][row], redM[1][row]);
    }
#pragma unroll
  for (int mi = 0; mi < 4; ++mi)
#pragma unroll
    for (int j = 0; j < 4; ++j) {
      float s = 0.f;
#pragma unroll
      for (int ni = 0; ni < 4; ++ni) {
        float e = __expf(acc[mi][ni][j] * BETA - fm[mi][j]);
        acc[mi][ni][j] = e;
        s += e;
      }
      s += __shfl_xor(s, 1);
      s += __shfl_xor(s, 2);
      s += __shfl_xor(s, 4);
      s += __shfl_xor(s, 8);
      wmax[mi][j] = s;  // reuse
    }
  if ((l & 15) == 0) {
#pragma unroll
    for (int mi = 0; mi < 4; ++mi)
#pragma unroll
      for (int j = 0; j < 4; ++j)
        redS[wc][wr * 64 + mi * 16 + (l >> 4) * 4 + j] = wmax[mi][j];
  }
  __syncthreads();

#pragma unroll
  for (int mi = 0; mi < 4; ++mi)
#pragma unroll
    for (int j = 0; j < 4; ++j) {
      int row = wr * 64 + mi * 16 + (l >> 4) * 4 + j;
      float invs = 1.0f / (redS[0][row] + redS[1][row]);
#pragma unroll
      for (int ni = 0; ni < 4; ++ni) {
        float rv = acc[mi][ni][j] * invs;
        rT[(wc * 64 + ni * 16 + (l & 15)) * 136 + row] = f2bf(rv);
      }
    }
  __syncthreads();

  {
    int c = t >> 1, half = t & 1;
    const unsigned short* src = &rT[c * 136 + half * 64];
    unsigned short* dst = &rbfT[(size_t)c * PADN + i0 + half * 64];
#pragma unroll
    for (int q = 0; q < 8; ++q)
      *(short8v*)(dst + q * 8) = *(const short8v*)(src + q * 8);
  }
  if (write_rbf) {
    int i = t >> 1, chalf = t & 1;
#pragma unroll
    for (int q = 0; q < 8; ++q) {
      short8v v;
#pragma unroll
      for (int e = 0; e < 8; ++e) v[e] = (short)rT[(chalf * 64 + q * 8 + e) * 136 + i];
      *(short8v*)&rbf[(size_t)(i0 + i) * KK + chalf * 64 + q * 8] = v;
    }
  }
}

// ---- cluster_r partials: crpart[c*8+p] = sum over part p's i-range of rbfT[c][i]
__launch_bounds__(256)
__global__ void crsum_kernel(const unsigned short* __restrict__ rbfT,
                             float* __restrict__ crpart) {
  int c = blockIdx.x, p = blockIdx.y, t = threadIdx.x;
  const unsigned short* row = rbfT + (size_t)c * PADN;
  int base = p * 12512;
  int end = base + 12512;
  if (end > NN) end = NN;
  float s = 0.f;
  for (int i = base + t * 8; i < end; i += 2048) {
    short8v v = *(const short8v*)(row + i);
#pragma unroll
    for (int u = 0; u < 8; ++u) s += bf2f((unsigned short)v[u]);
  }
  s = wave_reduce_sum(s);
  __shared__ float red[4];
  if ((t & 63) == 0) red[t >> 6] = s;
  __syncthreads();
  if (t == 0) crpart[c * 8 + p] = red[0] + red[1] + red[2] + red[3];
}

// ---- MFMA mu update. A (rbfT) + B (posbT) LDS dbuf, swizzled, T4 counted vmcnt.
__launch_bounds__(256, 2)
__global__ void muup_mfma(const unsigned short* __restrict__ rbfT,
                          const unsigned short* __restrict__ posbT,
                          unsigned short* __restrict__ part) {
  __shared__ __align__(16) unsigned short smem[32768];  // As[2][8192] | Bs[2][8192]
  unsigned short* As0 = smem;
  unsigned short* Bs0 = smem + 16384;
  int t = threadIdx.x;
  int w = t >> 6, l = t & 63;
  int wr = w >> 1, wc = w & 1;
  int ht = blockIdx.x, s = blockIdx.y;

  float4v acc[4][4];
#pragma unroll
  for (int mi = 0; mi < 4; ++mi)
#pragma unroll
    for (int ni = 0; ni < 4; ++ni) acc[mi][ni] = (float4v){0.f, 0.f, 0.f, 0.f};

  int rsub = l >> 3;
  int scol = ((l & 7) ^ rsub) * 8;  // shorts

  auto stage = [&](int buf, int ch) {
    size_t ib = (size_t)ch * 64;
#pragma unroll
    for (int j = 0; j < 4; ++j) {
      int v = w * 4 + j;
      int row = v * 8 + rsub;
      gload16(rbfT + (size_t)row * PADN + ib + scol, As0 + buf * 8192 + v * 512);
      gload16(posbT + (size_t)(ht * 128 + row) * PADN + ib + scol, Bs0 + buf * 8192 + v * 512);
    }
  };

  int ch = s;
  stage(0, ch);  // 8 loads in flight
  int cur = 0;
  for (; ch < NCHUNK; ch += NSPLIT) {
    int nxt = ch + NSPLIT;
    if (nxt < NCHUNK) {
      stage(cur ^ 1, nxt);
      asm volatile("s_waitcnt vmcnt(8)" ::: "memory");
    } else {
      asm volatile("s_waitcnt vmcnt(0)" ::: "memory");
    }
    __builtin_amdgcn_s_barrier();
    __builtin_amdgcn_sched_barrier(0);
    const char* ab = (const char*)(As0 + cur * 8192);
    const char* bb = (const char*)(Bs0 + cur * 8192);
#pragma unroll
    for (int ks = 0; ks < 2; ++ks) {
      short8v af[4], bfr[4];
      int kb = ks * 64 + (l >> 4) * 16;
      int rx = ((l & 7) << 4);
#pragma unroll
      for (int mi = 0; mi < 4; ++mi) {
        int row = wr * 64 + mi * 16 + (l & 15);
        af[mi] = *(const short8v*)(ab + row * 128 + (kb ^ rx));
      }
#pragma unroll
      for (int ni = 0; ni < 4; ++ni) {
        int row = wc * 64 + ni * 16 + (l & 15);
        bfr[ni] = *(const short8v*)(bb + row * 128 + (kb ^ rx));
      }
#pragma unroll
      for (int mi = 0; mi < 4; ++mi)
#pragma unroll
        for (int ni = 0; ni < 4; ++ni)
          acc[mi][ni] = __builtin_amdgcn_mfma_f32_16x16x32_bf16(af[mi], bfr[ni], acc[mi][ni], 0, 0, 0);
    }
    __builtin_amdgcn_sched_barrier(0);
    __builtin_amdgcn_s_barrier();
    __builtin_amdgcn_sched_barrier(0);
    cur ^= 1;
  }
#pragma unroll
  for (int mi = 0; mi < 4; ++mi)
#pragma unroll
    for (int ni = 0; ni < 4; ++ni)
#pragma unroll
      for (int j = 0; j < 4; ++j) {
        int c = wr * 64 + mi * 16 + (l >> 4) * 4 + j;
        int hh = wc * 64 + ni * 16 + (l & 15);
        part[((size_t)s * KK + c) * HH + ht * 128 + hh] = f2bf(acc[mi][ni][j]);
      }
}

// ---- fused fin+norm: v = (sum_s part)/cr; mub = normalize(v); mubT (last iter) = v
__global__ void finorm_kernel(const unsigned short* __restrict__ part,
                              const float* __restrict__ crpart,
                              unsigned short* __restrict__ mub,
                              unsigned short* __restrict__ mubT, int write_mubT) {
  int c = blockIdx.x, t = threadIdx.x;
  float cr = 0.f;
#pragma unroll
  for (int p = 0; p < 8; ++p) cr += crpart[c * 8 + p];
  float inv = 1.0f / cr;
  float s0 = 0.f, s1 = 0.f;
  const unsigned short* pb = part + (size_t)c * HH;
#pragma unroll 4
  for (int s2 = 0; s2 < NSPLIT; ++s2) {
    s0 += bf2f(pb[(size_t)s2 * KK * HH + t]);
    s1 += bf2f(pb[(size_t)s2 * KK * HH + t + 256]);
  }
  float v0 = s0 * inv, v1 = s1 * inv;
  if (write_mubT) {
    mubT[(size_t)t * KK + c] = f2bf(v0);
    mubT[(size_t)(t + 256) * KK + c] = f2bf(v1);
  }
  float ss = v0 * v0 + v1 * v1;
  ss = wave_reduce_sum(ss);
  __shared__ float red[4];
  if ((t & 63) == 0) red[t >> 6] = ss;
  __syncthreads();
  float rn = 1.0f / sqrtf(red[0] + red[1] + red[2] + red[3]);
  mub[c * HH + t] = f2bf(v0 * rn);
  mub[c * HH + t + 256] = f2bf(v1 * rn);
}

// ---- MFMA loss: cs = sigmoid(r@mu) via MFMA; sigma -> LDS; vectorized row-dot phase.
__launch_bounds__(512, 4)
__global__ void loss_mfma(const unsigned short* __restrict__ rbf,
                          const unsigned short* __restrict__ mubT,
                          const unsigned short* __restrict__ posb,
                          const float* __restrict__ neg,
                          const float* __restrict__ inv_norm,
                          const float* __restrict__ Wsv, float* __restrict__ loss_accum) {
  __shared__ __align__(16) unsigned short rS[128 * 128];   // 32KB [i][k] swizzled
  __shared__ __align__(16) unsigned short BsU[128 * 136];  // MFMA B (swizzled) / csS [row][136]
  __shared__ float WsS[HH];
  __shared__ float pcS[128], ncS[128], pgS[128], ngS[128];
  int t = threadIdx.x;
  int w = t >> 6, l = t & 63;
  int wr = w >> 1, wc = w & 1;
  int i0 = blockIdx.x * 128;

  {
    const char* gb = (const char*)rbf + (size_t)i0 * KK * 2;
#pragma unroll
    for (int j = 0; j < 4; ++j) {
      int v = w * 4 + j;
      int row = v * 4 + (l >> 4);
      int cb = ((l & 15) * 16) ^ ((row & 7) << 4);
      gload16(gb + (size_t)row * 256 + cb, (char*)rS + v * 1024);
    }
  }
  WsS[t] = Wsv[t];
  if (t < 128) {
    pcS[t] = 0.f; ncS[t] = 0.f; pgS[t] = 0.f; ngS[t] = 0.f;
  }

  for (int p = 0; p < 4; ++p) {
    __syncthreads();  // (a) prev dot done with csS; p=0: init; barrier drains vmcnt
    {
      const char* gb = (const char*)mubT + (size_t)p * 128 * 256;
#pragma unroll
      for (int j = 0; j < 4; ++j) {
        int v = w * 4 + j;
        int row = v * 4 + (l >> 4);
        int cb = ((l & 15) * 16) ^ ((row & 7) << 4);
        gload16(gb + (size_t)row * 256 + cb, (char*)BsU + v * 1024);
      }
    }
    __syncthreads();  // (b) BsU ready

    float4v acc[2][4];
#pragma unroll
    for (int mi = 0; mi < 2; ++mi)
#pragma unroll
      for (int ni = 0; ni < 4; ++ni) acc[mi][ni] = (float4v){0.f, 0.f, 0.f, 0.f};

#pragma unroll
    for (int ks = 0; ks < 4; ++ks) {
      short8v af[2], bfr[4];
      int kb = ks * 64 + (l >> 4) * 16;
#pragma unroll
      for (int mi = 0; mi < 2; ++mi) {
        int row = wr * 32 + mi * 16 + (l & 15);
        af[mi] = *(const short8v*)((const char*)rS + row * 256 + (kb ^ ((row & 7) << 4)));
      }
#pragma unroll
      for (int ni = 0; ni < 4; ++ni) {
        int hrow = wc * 64 + ni * 16 + (l & 15);
        bfr[ni] = *(const short8v*)((const char*)BsU + hrow * 256 + (kb ^ ((hrow & 7) << 4)));
      }
#pragma unroll
      for (int mi = 0; mi < 2; ++mi)
#pragma unroll
        for (int ni = 0; ni < 4; ++ni)
          acc[mi][ni] = __builtin_amdgcn_mfma_f32_16x16x32_bf16(af[mi], bfr[ni], acc[mi][ni], 0, 0, 0);
    }
    __syncthreads();  // (c) all MFMA reads of BsU done

    unsigned short* csS = BsU;
#pragma unroll
    for (int mi = 0; mi < 2; ++mi)
#pragma unroll
      for (int ni = 0; ni < 4; ++ni)
#pragma unroll
        for (int j = 0; j < 4; ++j) {
          int row = wr * 32 + mi * 16 + (l >> 4) * 4 + j;
          int col = wc * 64 + ni * 16 + (l & 15);
          csS[row * 136 + col] = f2bf(1.0f / (1.0f + __expf(-acc[mi][ni][j])));
        }
    __syncthreads();  // (d) csS ready

    {
      int rl = t >> 2;  // 0..127
      int q = t & 3;
      int gi = i0 + rl;
      bool valid = gi < NN;
      float pc = 0.f, nc = 0.f, pg = 0.f, ng = 0.f;
      const unsigned short* pr = posb + (size_t)gi * HH + p * 128;
      const float* nr = neg + (size_t)gi * HH + p * 128;
      const unsigned short* cr = csS + rl * 136;
#pragma unroll
      for (int e = 0; e < 4; ++e) {
        int cb = e * 32 + q * 8;
        short8v cs8 = *(const short8v*)(cr + cb);
        if (valid) {
          short8v pv8 = *(const short8v*)(pr + cb);
          float4 nv0 = *(const float4*)(nr + cb);
          float4 nv1 = *(const float4*)(nr + cb + 4);
#pragma unroll
          for (int u = 0; u < 8; ++u) {
            float sg = bf2f((unsigned short)cs8[u]);
            float pv = bf2f((unsigned short)pv8[u]);
            float nv = (u < 4) ? (&nv0.x)[u] : (&nv1.x)[u - 4];
            float wv = WsS[p * 128 + cb + u];
            pc = fmaf(sg, pv, pc);
            nc = fmaf(sg, nv, nc);
            pg = fmaf(wv, pv, pg);
            ng = fmaf(wv, nv, ng);
          }
        }
      }
      pc += __shfl_xor(pc, 1); pc += __shfl_xor(pc, 2);
      nc += __shfl_xor(nc, 1); nc += __shfl_xor(nc, 2);
      pg += __shfl_xor(pg, 1); pg += __shfl_xor(pg, 2);
      ng += __shfl_xor(ng, 1); ng += __shfl_xor(ng, 2);
      if (q == 0) {
        pcS[rl] += pc;
        ncS[rl] += nc;
        pgS[rl] += pg;
        ngS[rl] += ng;
      }
    }
  }
  __syncthreads();
  if (t < 128) {
    int gi = i0 + t;
    float contrib = 0.f;
    if (gi < NN) {
      float nrm = 1.0f / inv_norm[gi];  // ||pos||+eps: exact un-normalization
      float pg = pgS[t] * nrm;
      float pc = pcS[t] * nrm;
      float ng = ngS[t];
      float nc = ncS[t];
      contrib = 0.5f * (softplusf(-pg) + softplusf(ng)) +
                0.5f * (softplusf(-pc) + softplusf(nc));
    }
    contrib = wave_reduce_sum(contrib);
    if (l == 0) atomicAdd(loss_accum, contrib);
  }
}

__global__ void out_kernel(const float* __restrict__ loss_accum, float* __restrict__ out) {
  out[0] = loss_accum[0] * (1.0f / NN);
}

extern "C" void kernel_launch(void* const* d_in, const int* in_sizes, int n_in,
                              void* d_out, int out_size, void* d_ws, size_t ws_size,
                              hipStream_t stream) {
  const float* pos = (const float*)d_in[0];
  const float* neg = (const float*)d_in[1];
  const float* init = (const float*)d_in[2];
  const float* W = (const float*)d_in[3];
  float* out = (float*)d_out;

  char* ws = (char*)d_ws;
  size_t off = 0;
  auto alloc = [&](size_t bytes) {
    void* p = ws + off;
    off = (off + bytes + 255) & ~(size_t)255;
    return p;
  };
  unsigned short* posb = (unsigned short*)alloc((size_t)PADN * HH * 2);   // 102.5 MB
  unsigned short* posbT = (unsigned short*)alloc((size_t)HH * PADN * 2);  // 102.5 MB
  unsigned short* rbf = (unsigned short*)alloc((size_t)PADN * KK * 2);    // 25.6 MB
  unsigned short* rbfT = (unsigned short*)alloc((size_t)KK * PADN * 2);   // 25.6 MB
  unsigned short* part = (unsigned short*)alloc((size_t)NSPLIT * KK * HH * 2);  // 16.8 MB
  float* colpart = (float*)alloc((size_t)PREPB * HH * 4);                 // 2 MB
  float* inv_norm = (float*)alloc((size_t)NN * 4);
  unsigned short* mub = (unsigned short*)alloc((size_t)KK * HH * 2);
  unsigned short* mubT = (unsigned short*)alloc((size_t)KK * HH * 2);
  float* crpart = (float*)alloc(KK * 8 * 4);
  float* gs = (float*)alloc(HH * 4);
  float* Ws = (float*)alloc(HH * 4);
  float* loss_accum = (float*)alloc(16);

  hipMemsetAsync(loss_accum, 0, sizeof(float), stream);

  prep_kernel<<<PREPB, 256, 0, stream>>>(pos, inv_norm, colpart, posb);
  transpose_kernel<<<dim3(PADN / 64, HH / 64), 256, 0, stream>>>(posb, posbT);
  gs_kernel<<<1, 512, 0, stream>>>(colpart, gs);
  wsum_kernel<<<128, 256, 0, stream>>>(W, gs, Ws);

  norm_mu_kernel<<<KK, 256, 0, stream>>>(init, mub);
  for (int it = 0; it < ITERS; ++it) {
    dist_mfma<<<NBLK128, 256, 0, stream>>>(posb, mub, rbf, rbfT, it == ITERS - 1 ? 1 : 0);
    crsum_kernel<<<dim3(KK, 8), 256, 0, stream>>>(rbfT, crpart);
    muup_mfma<<<dim3(4, NSPLIT), 256, 0, stream>>>(rbfT, posbT, part);
    finorm_kernel<<<KK, 256, 0, stream>>>(part, crpart, mub, mubT, it == ITERS - 1 ? 1 : 0);
  }

  loss_mfma<<<NBLK128, 512, 0, stream>>>(rbf, mubT, posb, neg, inv_norm, Ws, loss_accum);
  out_kernel<<<1, 1, 0, stream>>>(loss_accum, out);
}

// Round 10
// 1215.183 us; speedup vs baseline: 1.5062x; 1.0172x over previous
//
#include <hip/hip_runtime.h>
#include <math.h>

#define NN 100000
#define PADN 100096    // 782*128
#define NBLK128 782
#define HH 512
#define KK 128
#define BETA 100.0f
#define EPSF 1e-8f
#define ITERS 11
#define NSPLIT 128
#define NCHUNK (PADN / 64)  // 1564
#define PREPB 1024

typedef __attribute__((ext_vector_type(8))) short short8v;
typedef __attribute__((ext_vector_type(4))) float float4v;

typedef const __attribute__((address_space(1))) void* gas_t;
typedef __attribute__((address_space(3))) void* las_t;

__device__ __forceinline__ void gload16(const void* g, void* l) {
  __builtin_amdgcn_global_load_lds((gas_t)g, (las_t)l, 16, 0, 0);
}

__device__ __forceinline__ unsigned short f2bf(float x) {
  unsigned int u = __float_as_uint(x);
  unsigned int r = (u + 0x7fff + ((u >> 16) & 1)) >> 16;
  return (unsigned short)r;
}
__device__ __forceinline__ float bf2f(unsigned short b) {
  return __uint_as_float((unsigned int)b << 16);
}

__device__ __forceinline__ float wave_reduce_sum(float v) {
#pragma unroll
  for (int off = 32; off > 0; off >>= 1) v += __shfl_xor(v, off);
  return v;
}
__device__ __forceinline__ float softplusf(float x) {
  return fmaxf(x, 0.0f) + log1pf(expf(-fabsf(x)));
}

// ---- fused prep: inv_norm, colpart (per-block colsum), posb (normalized bf16), pad-zero
__global__ void prep_kernel(const float* __restrict__ pos,
                            float* __restrict__ inv_norm,
                            float* __restrict__ colpart,
                            unsigned short* __restrict__ posb) {
  int t = threadIdx.x;
  int w = t >> 6, lane = t & 63;
  int gw = blockIdx.x * 4 + w;  // 0..4095
  float cpart[8] = {0, 0, 0, 0, 0, 0, 0, 0};
  for (int row = gw; row < NN; row += PREPB * 4) {
    const float* p = pos + (size_t)row * HH + lane * 8;
    float4 f0 = *(const float4*)p;
    float4 f1 = *(const float4*)(p + 4);
    float v[8] = {f0.x, f0.y, f0.z, f0.w, f1.x, f1.y, f1.z, f1.w};
    float ss = 0.f;
#pragma unroll
    for (int u = 0; u < 8; ++u) {
      ss += v[u] * v[u];
      cpart[u] += v[u];
    }
    ss = wave_reduce_sum(ss);
    float inv = 1.0f / (sqrtf(ss) + EPSF);
    if (lane == 0) inv_norm[row] = inv;
    short8v o;
#pragma unroll
    for (int u = 0; u < 8; ++u) o[u] = (short)f2bf(v[u] * inv);
    *(short8v*)&posb[(size_t)row * HH + lane * 8] = o;
  }
  {
    int idx = blockIdx.x * 256 + t;
    if (idx < (PADN - NN) * HH / 8) {
      short8v z = (short8v){0, 0, 0, 0, 0, 0, 0, 0};
      *(short8v*)&posb[(size_t)NN * HH + idx * 8] = z;
    }
  }
  __shared__ float cs[HH];
  cs[t] = 0.f;
  cs[t + 256] = 0.f;
  __syncthreads();
#pragma unroll
  for (int u = 0; u < 8; ++u) atomicAdd(&cs[lane * 8 + u], cpart[u]);
  __syncthreads();
  colpart[(size_t)blockIdx.x * HH + t] = cs[t];
  colpart[(size_t)blockIdx.x * HH + t + 256] = cs[t + 256];
}

// ---- bf16 transpose posb -> posbT (posb is L3-hot)
__launch_bounds__(256)
__global__ void transpose_kernel(const unsigned short* __restrict__ posb,
                                 unsigned short* __restrict__ posbT) {
  __shared__ unsigned short tile[64][72];
  int t = threadIdx.x;
  int i0 = blockIdx.x * 64, h0 = blockIdx.y * 64;
  int r = t >> 2, cq = (t & 3) * 16;
#pragma unroll
  for (int q = 0; q < 2; ++q) {
    short8v v = *(const short8v*)&posb[(size_t)(i0 + r) * HH + h0 + cq + q * 8];
#pragma unroll
    for (int e = 0; e < 8; ++e) tile[cq + q * 8 + e][r] = (unsigned short)v[e];
  }
  __syncthreads();
  int h = t >> 2, iq = (t & 3) * 16;
#pragma unroll
  for (int q = 0; q < 2; ++q)
    *(short8v*)&posbT[(size_t)(h0 + h) * PADN + i0 + iq + q * 8] =
        *(const short8v*)&tile[h][iq + q * 8];
}

// ---- gs[h] = sigmoid(sum_b colpart[b][h] / N)
__global__ void gs_kernel(const float* __restrict__ colpart, float* __restrict__ gs) {
  int t = threadIdx.x;  // 512
  float s = 0.f;
  for (int b = 0; b < PREPB; ++b) s += colpart[(size_t)b * HH + t];
  float m = s * (1.0f / NN);
  gs[t] = 1.0f / (1.0f + expf(-m));
}

// ---- Ws[j] = sum_h W[j][h]*gs[h]
__global__ void wsum_kernel(const float* __restrict__ W, const float* __restrict__ gs,
                            float* __restrict__ Ws) {
  int w = threadIdx.x >> 6, lane = threadIdx.x & 63;
  int row = blockIdx.x * 4 + w;
  const float* Wr = W + (size_t)row * HH;
  float s = 0.f;
#pragma unroll
  for (int j = 0; j < 8; ++j) s += Wr[lane + 64 * j] * gs[lane + 64 * j];
  s = wave_reduce_sum(s);
  if (lane == 0) Ws[row] = s;
}

// ---- mub (bf16) = row / ||row|| from fp32 src. Used once on init.
__global__ void norm_mu_kernel(const float* __restrict__ src, unsigned short* __restrict__ mub) {
  int k = blockIdx.x, t = threadIdx.x;
  float v0 = src[k * HH + t], v1 = src[k * HH + t + 256];
  float ss = v0 * v0 + v1 * v1;
  ss = wave_reduce_sum(ss);
  __shared__ float red[4];
  if ((t & 63) == 0) red[t >> 6] = ss;
  __syncthreads();
  float inv = 1.0f / sqrtf(red[0] + red[1] + red[2] + red[3]);
  mub[k * HH + t] = f2bf(v0 * inv);
  mub[k * HH + t + 256] = f2bf(v1 * inv);
}

// ---- MFMA dist + fused softmax. BM=128, 256 thr, 4x4 acc, swizzled A/B dbuf.
// T4 counted vmcnt; per-block cluster_r partials written to crblk (no atomics).
__launch_bounds__(256, 2)
__global__ void dist_mfma(const unsigned short* __restrict__ posb,
                          const unsigned short* __restrict__ mub,
                          unsigned short* __restrict__ rbf,
                          unsigned short* __restrict__ rbfT,
                          float* __restrict__ crblk,
                          int write_rbf) {
  __shared__ __align__(16) unsigned short smem[32768];  // 64KB: As[2][8192] | Bs[2][8192]
  unsigned short* As0 = smem;
  unsigned short* Bs0 = smem + 16384;
  unsigned short* rT = smem;  // [128 c][136] epilogue alias
  __shared__ float redM[2][128];
  __shared__ float redS[2][128];
  __shared__ float crS[2][128];

  int t = threadIdx.x;
  int w = t >> 6, l = t & 63;
  int wr = w >> 1, wc = w & 1;
  int i0 = blockIdx.x * 128;

  float4v acc[4][4];
#pragma unroll
  for (int mi = 0; mi < 4; ++mi)
#pragma unroll
    for (int ni = 0; ni < 4; ++ni) acc[mi][ni] = (float4v){0.f, 0.f, 0.f, 0.f};

  int rsub = l >> 3;
  int scol = ((l & 7) ^ rsub) * 8;  // shorts

  auto stage = [&](int buf, int ch) {
    int h0 = ch * 64;
#pragma unroll
    for (int j = 0; j < 4; ++j) {
      int v = w * 4 + j;
      int row = v * 8 + rsub;
      gload16(posb + (size_t)(i0 + row) * HH + h0 + scol, As0 + buf * 8192 + v * 512);
      gload16(mub + (size_t)row * HH + h0 + scol, Bs0 + buf * 8192 + v * 512);
    }
  };

  stage(0, 0);  // 8 loads in flight
  int cur = 0;
  for (int ch = 0; ch < 8; ++ch) {
    if (ch < 7) {
      stage(cur ^ 1, ch + 1);  // +8 loads (16 outstanding)
      asm volatile("s_waitcnt vmcnt(8)" ::: "memory");  // wait cur's 8; prefetch stays in flight
    } else {
      asm volatile("s_waitcnt vmcnt(0)" ::: "memory");
    }
    __builtin_amdgcn_s_barrier();
    __builtin_amdgcn_sched_barrier(0);
    const char* ab = (const char*)(As0 + cur * 8192);
    const char* bb = (const char*)(Bs0 + cur * 8192);
#pragma unroll
    for (int ks = 0; ks < 2; ++ks) {
      short8v af[4], bfr[4];
      int kb = ks * 64 + (l >> 4) * 16;
      int rx = ((l & 7) << 4);
#pragma unroll
      for (int mi = 0; mi < 4; ++mi) {
        int row = wr * 64 + mi * 16 + (l & 15);
        af[mi] = *(const short8v*)(ab + row * 128 + (kb ^ rx));
      }
#pragma unroll
      for (int ni = 0; ni < 4; ++ni) {
        int row = wc * 64 + ni * 16 + (l & 15);
        bfr[ni] = *(const short8v*)(bb + row * 128 + (kb ^ rx));
      }
#pragma unroll
      for (int mi = 0; mi < 4; ++mi)
#pragma unroll
        for (int ni = 0; ni < 4; ++ni)
          acc[mi][ni] = __builtin_amdgcn_mfma_f32_16x16x32_bf16(af[mi], bfr[ni], acc[mi][ni], 0, 0, 0);
    }
    __builtin_amdgcn_sched_barrier(0);  // no motion of next stage above this point
    __builtin_amdgcn_s_barrier();       // all waves done reading cur before it is restaged
    __builtin_amdgcn_sched_barrier(0);
    cur ^= 1;
  }

  // ---- softmax epilogue. row(local) = wr*64+mi*16+(l>>4)*4+j, col = wc*64+ni*16+(l&15)
  float wmax[4][4];
#pragma unroll
  for (int mi = 0; mi < 4; ++mi)
#pragma unroll
    for (int j = 0; j < 4; ++j) {
      float m = fmaxf(fmaxf(acc[mi][0][j], acc[mi][1][j]), fmaxf(acc[mi][2][j], acc[mi][3][j])) * BETA;
      m = fmaxf(m, __shfl_xor(m, 1));
      m = fmaxf(m, __shfl_xor(m, 2));
      m = fmaxf(m, __shfl_xor(m, 4));
      m = fmaxf(m, __shfl_xor(m, 8));
      wmax[mi][j] = m;
    }
  if ((l & 15) == 0) {
#pragma unroll
    for (int mi = 0; mi < 4; ++mi)
#pragma unroll
      for (int j = 0; j < 4; ++j)
        redM[wc][wr * 64 + mi * 16 + (l >> 4) * 4 + j] = wmax[mi][j];
  }
  __syncthreads();
  float fm[4][4];
#pragma unroll
  for (int mi = 0; mi < 4; ++mi)
#pragma unroll
    for (int j = 0; j < 4; ++j) {
      int row = wr * 64 + mi * 16 + (l >> 4) * 4 + j;
      fm[mi][j] = fmaxf(redM[0][row], redM[1][row]);
    }
#pragma unroll
  for (int mi = 0; mi < 4; ++mi)
#pragma unroll
    for (int j = 0; j < 4; ++j) {
      float s = 0.f;
#pragma unroll
      for (int ni = 0; ni < 4; ++ni) {
        float e = __expf(acc[mi][ni][j] * BETA - fm[mi][j]);
        acc[mi][ni][j] = e;
        s += e;
      }
      s += __shfl_xor(s, 1);
      s += __shfl_xor(s, 2);
      s += __shfl_xor(s, 4);
      s += __shfl_xor(s, 8);
      wmax[mi][j] = s;  // reuse
    }
  if ((l & 15) == 0) {
#pragma unroll
    for (int mi = 0; mi < 4; ++mi)
#pragma unroll
      for (int j = 0; j < 4; ++j)
        redS[wc][wr * 64 + mi * 16 + (l >> 4) * 4 + j] = wmax[mi][j];
  }
  __syncthreads();

  float cpart[4] = {0.f, 0.f, 0.f, 0.f};
#pragma unroll
  for (int mi = 0; mi < 4; ++mi)
#pragma unroll
    for (int j = 0; j < 4; ++j) {
      int row = wr * 64 + mi * 16 + (l >> 4) * 4 + j;
      float invs = 1.0f / (redS[0][row] + redS[1][row]);
      bool valid = (i0 + row) < NN;
#pragma unroll
      for (int ni = 0; ni < 4; ++ni) {
        float rv = acc[mi][ni][j] * invs;
        if (valid) cpart[ni] += rv;
        rT[(wc * 64 + ni * 16 + (l & 15)) * 136 + row] = f2bf(rv);
      }
    }
#pragma unroll
  for (int ni = 0; ni < 4; ++ni) {
    float c = cpart[ni];
    c += __shfl_xor(c, 16);
    c += __shfl_xor(c, 32);
    if (l < 16) crS[wr][wc * 64 + ni * 16 + l] = c;
  }
  __syncthreads();
  if (t < 128) crblk[(size_t)blockIdx.x * KK + t] = crS[0][t] + crS[1][t];

  {
    int c = t >> 1, half = t & 1;
    const unsigned short* src = &rT[c * 136 + half * 64];
    unsigned short* dst = &rbfT[(size_t)c * PADN + i0 + half * 64];
#pragma unroll
    for (int q = 0; q < 8; ++q)
      *(short8v*)(dst + q * 8) = *(const short8v*)(src + q * 8);
  }
  if (write_rbf) {
    int i = t >> 1, chalf = t & 1;
#pragma unroll
    for (int q = 0; q < 8; ++q) {
      short8v v;
#pragma unroll
      for (int e = 0; e < 8; ++e) v[e] = (short)rT[(chalf * 64 + q * 8 + e) * 136 + i];
      *(short8v*)&rbf[(size_t)(i0 + i) * KK + chalf * 64 + q * 8] = v;
    }
  }
}

// ---- MFMA mu update. A (rbfT) + B (posbT) LDS dbuf, swizzled, T4 counted vmcnt.
__launch_bounds__(256, 2)
__global__ void muup_mfma(const unsigned short* __restrict__ rbfT,
                          const unsigned short* __restrict__ posbT,
                          unsigned short* __restrict__ part) {
  __shared__ __align__(16) unsigned short smem[32768];  // As[2][8192] | Bs[2][8192]
  unsigned short* As0 = smem;
  unsigned short* Bs0 = smem + 16384;
  int t = threadIdx.x;
  int w = t >> 6, l = t & 63;
  int wr = w >> 1, wc = w & 1;
  int ht = blockIdx.x, s = blockIdx.y;

  float4v acc[4][4];
#pragma unroll
  for (int mi = 0; mi < 4; ++mi)
#pragma unroll
    for (int ni = 0; ni < 4; ++ni) acc[mi][ni] = (float4v){0.f, 0.f, 0.f, 0.f};

  int rsub = l >> 3;
  int scol = ((l & 7) ^ rsub) * 8;  // shorts

  auto stage = [&](int buf, int ch) {
    size_t ib = (size_t)ch * 64;
#pragma unroll
    for (int j = 0; j < 4; ++j) {
      int v = w * 4 + j;
      int row = v * 8 + rsub;
      gload16(rbfT + (size_t)row * PADN + ib + scol, As0 + buf * 8192 + v * 512);
      gload16(posbT + (size_t)(ht * 128 + row) * PADN + ib + scol, Bs0 + buf * 8192 + v * 512);
    }
  };

  int ch = s;
  stage(0, ch);  // 8 loads in flight
  int cur = 0;
  for (; ch < NCHUNK; ch += NSPLIT) {
    int nxt = ch + NSPLIT;
    if (nxt < NCHUNK) {
      stage(cur ^ 1, nxt);
      asm volatile("s_waitcnt vmcnt(8)" ::: "memory");
    } else {
      asm volatile("s_waitcnt vmcnt(0)" ::: "memory");
    }
    __builtin_amdgcn_s_barrier();
    __builtin_amdgcn_sched_barrier(0);
    const char* ab = (const char*)(As0 + cur * 8192);
    const char* bb = (const char*)(Bs0 + cur * 8192);
#pragma unroll
    for (int ks = 0; ks < 2; ++ks) {
      short8v af[4], bfr[4];
      int kb = ks * 64 + (l >> 4) * 16;
      int rx = ((l & 7) << 4);
#pragma unroll
      for (int mi = 0; mi < 4; ++mi) {
        int row = wr * 64 + mi * 16 + (l & 15);
        af[mi] = *(const short8v*)(ab + row * 128 + (kb ^ rx));
      }
#pragma unroll
      for (int ni = 0; ni < 4; ++ni) {
        int row = wc * 64 + ni * 16 + (l & 15);
        bfr[ni] = *(const short8v*)(bb + row * 128 + (kb ^ rx));
      }
#pragma unroll
      for (int mi = 0; mi < 4; ++mi)
#pragma unroll
        for (int ni = 0; ni < 4; ++ni)
          acc[mi][ni] = __builtin_amdgcn_mfma_f32_16x16x32_bf16(af[mi], bfr[ni], acc[mi][ni], 0, 0, 0);
    }
    __builtin_amdgcn_sched_barrier(0);
    __builtin_amdgcn_s_barrier();
    __builtin_amdgcn_sched_barrier(0);
    cur ^= 1;
  }
#pragma unroll
  for (int mi = 0; mi < 4; ++mi)
#pragma unroll
    for (int ni = 0; ni < 4; ++ni)
#pragma unroll
      for (int j = 0; j < 4; ++j) {
        int c = wr * 64 + mi * 16 + (l >> 4) * 4 + j;
        int hh = wc * 64 + ni * 16 + (l & 15);
        part[((size_t)s * KK + c) * HH + ht * 128 + hh] = f2bf(acc[mi][ni][j]);
      }
}

// ---- fused fin+norm: cr = sum_b crblk; v = (sum_s part)/cr; mub = normalize(v); mubT (last)
__global__ void finorm_kernel(const unsigned short* __restrict__ part,
                              const float* __restrict__ crblk,
                              unsigned short* __restrict__ mub,
                              unsigned short* __restrict__ mubT, int write_mubT) {
  int c = blockIdx.x, t = threadIdx.x;
  __shared__ float credL[4];
  float crp = 0.f;
  for (int b = t; b < NBLK128; b += 256) crp += crblk[(size_t)b * KK + c];
  crp = wave_reduce_sum(crp);
  if ((t & 63) == 0) credL[t >> 6] = crp;
  __syncthreads();
  float cr = credL[0] + credL[1] + credL[2] + credL[3];
  float inv = 1.0f / cr;
  float s0 = 0.f, s1 = 0.f;
  const unsigned short* pb = part + (size_t)c * HH;
#pragma unroll 4
  for (int s2 = 0; s2 < NSPLIT; ++s2) {
    s0 += bf2f(pb[(size_t)s2 * KK * HH + t]);
    s1 += bf2f(pb[(size_t)s2 * KK * HH + t + 256]);
  }
  float v0 = s0 * inv, v1 = s1 * inv;
  if (write_mubT) {
    mubT[(size_t)t * KK + c] = f2bf(v0);
    mubT[(size_t)(t + 256) * KK + c] = f2bf(v1);
  }
  float ss = v0 * v0 + v1 * v1;
  ss = wave_reduce_sum(ss);
  __shared__ float red[4];
  if ((t & 63) == 0) red[t >> 6] = ss;
  __syncthreads();
  float rn = 1.0f / sqrtf(red[0] + red[1] + red[2] + red[3]);
  mub[c * HH + t] = f2bf(v0 * rn);
  mub[c * HH + t + 256] = f2bf(v1 * rn);
}

// ---- MFMA loss: cs = sigmoid(r@mu) via MFMA; sigma -> LDS (XOR-swizzled); row-dot phase.
__launch_bounds__(512, 4)
__global__ void loss_mfma(const unsigned short* __restrict__ rbf,
                          const unsigned short* __restrict__ mubT,
                          const unsigned short* __restrict__ posb,
                          const float* __restrict__ neg,
                          const float* __restrict__ inv_norm,
                          const float* __restrict__ Wsv, float* __restrict__ loss_accum) {
  __shared__ __align__(16) unsigned short rS[128 * 128];   // 32KB [i][k] swizzled
  __shared__ __align__(16) unsigned short BsU[128 * 136];  // MFMA B (swizzled) / csS [row][136]
  __shared__ float WsS[HH];
  __shared__ float pcS[128], ncS[128], pgS[128], ngS[128];
  int t = threadIdx.x;
  int w = t >> 6, l = t & 63;
  int wr = w >> 1, wc = w & 1;
  int i0 = blockIdx.x * 128;

  {
    const char* gb = (const char*)rbf + (size_t)i0 * KK * 2;
#pragma unroll
    for (int j = 0; j < 4; ++j) {
      int v = w * 4 + j;
      int row = v * 4 + (l >> 4);
      int cb = ((l & 15) * 16) ^ ((row & 7) << 4);
      gload16(gb + (size_t)row * 256 + cb, (char*)rS + v * 1024);
    }
  }
  WsS[t] = Wsv[t];
  if (t < 128) {
    pcS[t] = 0.f; ncS[t] = 0.f; pgS[t] = 0.f; ngS[t] = 0.f;
  }

  for (int p = 0; p < 4; ++p) {
    __syncthreads();  // (a) prev dot done with csS; p=0: init; barrier drains vmcnt
    {
      const char* gb = (const char*)mubT + (size_t)p * 128 * 256;
#pragma unroll
      for (int j = 0; j < 4; ++j) {
        int v = w * 4 + j;
        int row = v * 4 + (l >> 4);
        int cb = ((l & 15) * 16) ^ ((row & 7) << 4);
        gload16(gb + (size_t)row * 256 + cb, (char*)BsU + v * 1024);
      }
    }
    __syncthreads();  // (b) BsU ready

    float4v acc[2][4];
#pragma unroll
    for (int mi = 0; mi < 2; ++mi)
#pragma unroll
      for (int ni = 0; ni < 4; ++ni) acc[mi][ni] = (float4v){0.f, 0.f, 0.f, 0.f};

#pragma unroll
    for (int ks = 0; ks < 4; ++ks) {
      short8v af[2], bfr[4];
      int kb = ks * 64 + (l >> 4) * 16;
#pragma unroll
      for (int mi = 0; mi < 2; ++mi) {
        int row = wr * 32 + mi * 16 + (l & 15);
        af[mi] = *(const short8v*)((const char*)rS + row * 256 + (kb ^ ((row & 7) << 4)));
      }
#pragma unroll
      for (int ni = 0; ni < 4; ++ni) {
        int hrow = wc * 64 + ni * 16 + (l & 15);
        bfr[ni] = *(const short8v*)((const char*)BsU + hrow * 256 + (kb ^ ((hrow & 7) << 4)));
      }
#pragma unroll
      for (int mi = 0; mi < 2; ++mi)
#pragma unroll
        for (int ni = 0; ni < 4; ++ni)
          acc[mi][ni] = __builtin_amdgcn_mfma_f32_16x16x32_bf16(af[mi], bfr[ni], acc[mi][ni], 0, 0, 0);
    }
    __syncthreads();  // (c) all MFMA reads of BsU done

    // sigma -> csS, 16B-slot XOR swizzle: byte = row*272 + ((col*2) ^ ((row&7)<<4))
    unsigned short* csS = BsU;
#pragma unroll
    for (int mi = 0; mi < 2; ++mi)
#pragma unroll
      for (int ni = 0; ni < 4; ++ni)
#pragma unroll
        for (int j = 0; j < 4; ++j) {
          int row = wr * 32 + mi * 16 + (l >> 4) * 4 + j;
          int col = wc * 64 + ni * 16 + (l & 15);
          int cbyte = (col * 2) ^ ((row & 7) << 4);
          *(unsigned short*)((char*)csS + row * 272 + cbyte) =
              f2bf(1.0f / (1.0f + __expf(-acc[mi][ni][j])));
        }
    __syncthreads();  // (d) csS ready

    {
      int rl = t >> 2;  // 0..127
      int q = t & 3;
      int gi = i0 + rl;
      bool valid = gi < NN;
      float pc = 0.f, nc = 0.f, pg = 0.f, ng = 0.f;
      const unsigned short* pr = posb + (size_t)gi * HH + p * 128;
      const float* nr = neg + (size_t)gi * HH + p * 128;
      const char* cr8 = (const char*)csS + rl * 272;
      int rx = (rl & 7) << 4;
#pragma unroll
      for (int e = 0; e < 4; ++e) {
        int cb = e * 32 + q * 8;          // shorts
        int cb2 = (cb * 2) ^ rx;          // swizzled byte offset
        short8v cs8 = *(const short8v*)(cr8 + cb2);
        if (valid) {
          short8v pv8 = *(const short8v*)(pr + cb);
          float4 nv0 = *(const float4*)(nr + cb);
          float4 nv1 = *(const float4*)(nr + cb + 4);
#pragma unroll
          for (int u = 0; u < 8; ++u) {
            float sg = bf2f((unsigned short)cs8[u]);
            float pv = bf2f((unsigned short)pv8[u]);
            float nv = (u < 4) ? (&nv0.x)[u] : (&nv1.x)[u - 4];
            float wv = WsS[p * 128 + cb + u];
            pc = fmaf(sg, pv, pc);
            nc = fmaf(sg, nv, nc);
            pg = fmaf(wv, pv, pg);
            ng = fmaf(wv, nv, ng);
          }
        }
      }
      pc += __shfl_xor(pc, 1); pc += __shfl_xor(pc, 2);
      nc += __shfl_xor(nc, 1); nc += __shfl_xor(nc, 2);
      pg += __shfl_xor(pg, 1); pg += __shfl_xor(pg, 2);
      ng += __shfl_xor(ng, 1); ng += __shfl_xor(ng, 2);
      if (q == 0) {
        pcS[rl] += pc;
        ncS[rl] += nc;
        pgS[rl] += pg;
        ngS[rl] += ng;
      }
    }
  }
  __syncthreads();
  if (t < 128) {
    int gi = i0 + t;
    float contrib = 0.f;
    if (gi < NN) {
      float nrm = 1.0f / inv_norm[gi];  // ||pos||+eps: exact un-normalization
      float pg = pgS[t] * nrm;
      float pc = pcS[t] * nrm;
      float ng = ngS[t];
      float nc = ncS[t];
      contrib = 0.5f * (softplusf(-pg) + softplusf(ng)) +
                0.5f * (softplusf(-pc) + softplusf(nc));
    }
    contrib = wave_reduce_sum(contrib);
    if (l == 0) atomicAdd(loss_accum, contrib);
  }
}

__global__ void out_kernel(const float* __restrict__ loss_accum, float* __restrict__ out) {
  out[0] = loss_accum[0] * (1.0f / NN);
}

extern "C" void kernel_launch(void* const* d_in, const int* in_sizes, int n_in,
                              void* d_out, int out_size, void* d_ws, size_t ws_size,
                              hipStream_t stream) {
  const float* pos = (const float*)d_in[0];
  const float* neg = (const float*)d_in[1];
  const float* init = (const float*)d_in[2];
  const float* W = (const float*)d_in[3];
  float* out = (float*)d_out;

  char* ws = (char*)d_ws;
  size_t off = 0;
  auto alloc = [&](size_t bytes) {
    void* p = ws + off;
    off = (off + bytes + 255) & ~(size_t)255;
    return p;
  };
  unsigned short* posb = (unsigned short*)alloc((size_t)PADN * HH * 2);   // 102.5 MB
  unsigned short* posbT = (unsigned short*)alloc((size_t)HH * PADN * 2);  // 102.5 MB
  unsigned short* rbf = (unsigned short*)alloc((size_t)PADN * KK * 2);    // 25.6 MB
  unsigned short* rbfT = (unsigned short*)alloc((size_t)KK * PADN * 2);   // 25.6 MB
  unsigned short* part = (unsigned short*)alloc((size_t)NSPLIT * KK * HH * 2);  // 16.8 MB
  float* colpart = (float*)alloc((size_t)PREPB * HH * 4);                 // 2 MB
  float* crblk = (float*)alloc((size_t)NBLK128 * KK * 4);                 // 400 KB
  float* inv_norm = (float*)alloc((size_t)NN * 4);
  unsigned short* mub = (unsigned short*)alloc((size_t)KK * HH * 2);
  unsigned short* mubT = (unsigned short*)alloc((size_t)KK * HH * 2);
  float* gs = (float*)alloc(HH * 4);
  float* Ws = (float*)alloc(HH * 4);
  float* loss_accum = (float*)alloc(16);

  hipMemsetAsync(loss_accum, 0, sizeof(float), stream);

  prep_kernel<<<PREPB, 256, 0, stream>>>(pos, inv_norm, colpart, posb);
  transpose_kernel<<<dim3(PADN / 64, HH / 64), 256, 0, stream>>>(posb, posbT);
  gs_kernel<<<1, 512, 0, stream>>>(colpart, gs);
  wsum_kernel<<<128, 256, 0, stream>>>(W, gs, Ws);

  norm_mu_kernel<<<KK, 256, 0, stream>>>(init, mub);
  for (int it = 0; it < ITERS; ++it) {
    dist_mfma<<<NBLK128, 256, 0, stream>>>(posb, mub, rbf, rbfT, crblk, it == ITERS - 1 ? 1 : 0);
    muup_mfma<<<dim3(4, NSPLIT), 256, 0, stream>>>(rbfT, posbT, part);
    finorm_kernel<<<KK, 256, 0, stream>>>(part, crblk, mub, mubT, it == ITERS - 1 ? 1 : 0);
  }

  loss_mfma<<<NBLK128, 512, 0, stream>>>(rbf, mubT, posb, neg, inv_norm, Ws, loss_accum);
  out_kernel<<<1, 1, 0, stream>>>(loss_accum, out);
}